// Round 5
// baseline (591.226 us; speedup 1.0000x reference)
//
#include <hip/hip_runtime.h>
#include <math.h>

#define LAYERS 2
#define HIDDEN 512
#define FFN_DIM 2048
#define HEADS 8
#define SLEN 2048
#define BSZ 2
#define MROWS 4096
#define ATT_SCALING 0.125f
#define LN_EPS 1e-5f
#define SCALE_BASE 512.0f
#define LOG2E 1.4426950408889634f

typedef unsigned short u16;
typedef unsigned int u32;
typedef __attribute__((ext_vector_type(8))) short bf16x8;   // 8 bf16 = 4 VGPR
typedef __attribute__((ext_vector_type(4))) float f32x4;

__device__ __forceinline__ float bf2f(u16 u) {
    union { u32 i; float f; } v; v.i = ((u32)u) << 16; return v.f;
}
__device__ __forceinline__ u16 f2bf(float f) {
    union { float f; u32 i; } v; v.f = f;
    u32 r = v.i + 0x7FFFu + ((v.i >> 16) & 1u);   // RNE
    return (u16)(r >> 16);
}
__device__ __forceinline__ void async16(const void* g, void* l) {
    __builtin_amdgcn_global_load_lds((const __attribute__((address_space(1))) void*)g,
                                     (__attribute__((address_space(3))) void*)l, 16, 0, 0);
}

// ---------------------------------------------------------------------------
// fp32 [K][N] -> bf16 [N][K] transpose (weights prep)
// ---------------------------------------------------------------------------
__global__ __launch_bounds__(256) void wtrans(const float* __restrict__ in,
                                              u16* __restrict__ out,
                                              int K, int N) {
    __shared__ float t[32][33];
    int tx = threadIdx.x & 31, ty = threadIdx.x >> 5;       // 32 x 8
    int k0 = blockIdx.y * 32, n0 = blockIdx.x * 32;
#pragma unroll
    for (int i = 0; i < 4; i++)
        t[ty + 8 * i][tx] = in[(size_t)(k0 + ty + 8 * i) * N + n0 + tx];
    __syncthreads();
#pragma unroll
    for (int i = 0; i < 4; i++)
        out[(size_t)(n0 + ty + 8 * i) * K + k0 + tx] = f2bf(t[tx][ty + 8 * i]);
}

// ---------------------------------------------------------------------------
// x fp32 -> residual fp32 copy + bf16 copy
// ---------------------------------------------------------------------------
__global__ __launch_bounds__(256) void cvt_x(const float* __restrict__ x,
                                             float* __restrict__ Af,
                                             u16* __restrict__ Ab) {
    int i = blockIdx.x * 256 + threadIdx.x;
    float v = x[i];
    Af[i] = v;
    Ab[i] = f2bf(v);
}

// ---------------------------------------------------------------------------
// xPos cos/sin table: tab[s*32+j] = (cos*scale, sin*scale)
// ---------------------------------------------------------------------------
__global__ __launch_bounds__(256) void xpos_table(float2* __restrict__ tab) {
    int idx = blockIdx.x * 256 + threadIdx.x;   // 2048*32 = 65536
    int j = idx & 31;
    int s = idx >> 5;
    float base = (2.0f * j + 0.4f * 64.0f) / (1.4f * 64.0f);
    float pos = (float)(s - 1024);
    float scale = powf(base, pos / SCALE_BASE);
    float inv_freq = powf(10000.0f, -(float)j / 32.0f);
    float ang = (float)s * inv_freq;
    tab[idx] = make_float2(cosf(ang) * scale, sinf(ang) * scale);
}

// ---------------------------------------------------------------------------
// xPos applied in-place to Q (cols h*64+..) and K (cols 512+h*64+..) of QKV
// bf16, packed u32 accesses. Q additionally scaled by LOG2E so attention
// softmax can use native exp2.
// ---------------------------------------------------------------------------
__global__ __launch_bounds__(256) void xpos_kernel(u16* __restrict__ QKV,
                                                   const float2* __restrict__ tab) {
    int idx = blockIdx.x * 256 + threadIdx.x;   // 2^20
    int j = idx & 31;
    int h = (idx >> 5) & 7;
    int s = (idx >> 8) & 2047;
    int b = idx >> 19;

    float2 cssn = tab[s * 32 + j];
    float cs = cssn.x, sn = cssn.y;

    size_t off = (size_t)(b * SLEN + s) * 2048 + h * 64 + 2 * j;
    u32* pq = (u32*)(QKV + off);
    u32* pk = (u32*)(QKV + off + 512);

    u32 qv = *pq;
    float q0 = bf2f((u16)(qv & 0xffff)), q1 = bf2f((u16)(qv >> 16));
    *pq = (u32)f2bf((q0 * cs - q1 * sn) * LOG2E) |
          ((u32)f2bf((q1 * cs + q0 * sn) * LOG2E) << 16);

    u32 kv = *pk;
    float k0 = bf2f((u16)(kv & 0xffff)), k1 = bf2f((u16)(kv >> 16));
    *pk = (u32)f2bf(k0 * cs - k1 * sn) | ((u32)f2bf(k1 * cs + k0 * sn) << 16);
}

// ---------------------------------------------------------------------------
// V section of QKV -> VT[(b*8+h)*128 + v][s]  (bf16 -> bf16 transpose)
// ---------------------------------------------------------------------------
__global__ __launch_bounds__(256) void vtrans(const u16* __restrict__ QKV,
                                              u16* __restrict__ VT) {
    __shared__ u16 t[64][65];
    int b = blockIdx.z >> 3, h = blockIdx.z & 7;
    int s0 = blockIdx.x * 64, v0 = blockIdx.y * 64;
    int tid = threadIdx.x;
#pragma unroll
    for (int i = 0; i < 16; i++) {
        int e = tid + i * 256; int r = e >> 6, c = e & 63;      // r: s, c: v
        t[r][c] = QKV[(size_t)(b * SLEN + s0 + r) * 2048 + 1024 + h * 128 + v0 + c];
    }
    __syncthreads();
#pragma unroll
    for (int i = 0; i < 16; i++) {
        int e = tid + i * 256; int r = e >> 6, c = e & 63;      // r: v, c: s
        VT[(size_t)((b * 8 + h) * 128 + v0 + r) * 2048 + s0 + c] = t[c][r];
    }
}

// ---------------------------------------------------------------------------
// MFMA GEMM, software-pipelined: single barrier per K-tile, loads for tile
// t+1 issued after the barrier so they stay in flight across compute(t).
// C[M,N] = A[M,K] @ W[K,N], W given as WT[N][K] (both bf16). BK=32.
// ---------------------------------------------------------------------------
template <int BM, int BN, int WM, int OUTF32, int BIAS, int RELU>
__global__ __launch_bounds__(256) void gemm_mfma(const u16* __restrict__ A,
                                                 const u16* __restrict__ WT,
                                                 const float* __restrict__ bias,
                                                 void* __restrict__ Cout,
                                                 int M, int N, int K) {
    constexpr int WN = 4 / WM;
    constexpr int AM = BM / (WM * 16);
    constexpr int AN = BN / (WN * 16);
    constexpr int AIT = BM / 64;
    constexpr int BIT = BN / 64;

    __shared__ u16 As[2][BM * 32];
    __shared__ u16 Bs[2][BN * 32];

    const int tid  = threadIdx.x;
    const int wave = tid >> 6;
    const int lane = tid & 63;
    const int quad = lane >> 4;
    const int l15  = lane & 15;
    const int wm = wave % WM;
    const int wn = wave / WM;

    const int tm = blockIdx.y * BM;
    const int tn = blockIdx.x * BN;

    auto issue = [&](int kt, int buf) {
#pragma unroll
        for (int it = 0; it < AIT; it++) {
            int cid = it * 256 + tid;
            async16(A + (size_t)(tm + (cid >> 2)) * K + kt + (cid & 3) * 8,
                    (char*)As[buf] + (it * 256 + wave * 64) * 16);
        }
#pragma unroll
        for (int it = 0; it < BIT; it++) {
            int cid = it * 256 + tid;
            async16(WT + (size_t)(tn + (cid >> 2)) * K + kt + (cid & 3) * 8,
                    (char*)Bs[buf] + (it * 256 + wave * 64) * 16);
        }
    };

    f32x4 acc[AM][AN];
#pragma unroll
    for (int i = 0; i < AM; i++)
#pragma unroll
        for (int j = 0; j < AN; j++) acc[i][j] = (f32x4){0.f, 0.f, 0.f, 0.f};

    const int nk = K >> 5;
    issue(0, 0);

    for (int t = 0; t < nk; t++) {
        __syncthreads();             // implicit vmcnt(0) drain: loads(t) done
        if (t + 1 < nk) issue((t + 1) << 5, (t + 1) & 1);
        const int buf = t & 1;

        bf16x8 af[AM], bfr[AN];
#pragma unroll
        for (int i = 0; i < AM; i++)
            af[i] = *(const bf16x8*)((const char*)As[buf] +
                     ((wm * (AM * 16) + i * 16 + l15) * 4 + quad) * 16);
#pragma unroll
        for (int j = 0; j < AN; j++)
            bfr[j] = *(const bf16x8*)((const char*)Bs[buf] +
                     ((wn * (AN * 16) + j * 16 + l15) * 4 + quad) * 16);
#pragma unroll
        for (int i = 0; i < AM; i++)
#pragma unroll
            for (int j = 0; j < AN; j++)
                acc[i][j] = __builtin_amdgcn_mfma_f32_16x16x32_bf16(af[i], bfr[j],
                                                                    acc[i][j], 0, 0, 0);
    }

#pragma unroll
    for (int i = 0; i < AM; i++) {
#pragma unroll
        for (int j = 0; j < AN; j++) {
            int col = tn + wn * (AN * 16) + j * 16 + l15;
            float bv = BIAS ? bias[col] : 0.0f;
#pragma unroll
            for (int r = 0; r < 4; r++) {
                int row = tm + wm * (AM * 16) + i * 16 + quad * 4 + r;
                float v = acc[i][j][r] + bv;
                if (RELU) v = fmaxf(v, 0.0f);
                if (OUTF32) ((float*)Cout)[(size_t)row * N + col] = v;
                else        ((u16*)Cout)[(size_t)row * N + col] = f2bf(v);
            }
        }
    }
}

// ---------------------------------------------------------------------------
// MFMA flash attention v2.
//  - K B-fragments loaded directly from global (L1-served, identical across
//    the 4 waves) -- no Ks LDS stage.
//  - Vs double-buffered in LDS (32 KB), single barrier per key-tile.
//  - Pl: XOR-swizzled 16B chunks (chunk ^ (row&7)) -> conflict-optimal reads,
//    zero padding; 8 KB total. LDS = 40 KB exactly -> 4 blocks/CU.
//  - Softmax in exp2 domain (Q pre-scaled by LOG2E in xpos).
// ---------------------------------------------------------------------------
__global__ __launch_bounds__(256, 4) void flash_attn_mfma(const u16* __restrict__ QKV,
                                                          const u16* __restrict__ VT,
                                                          u16* __restrict__ O) {
    const int q0 = blockIdx.x * 64;
    const int h  = blockIdx.y;
    const int b  = blockIdx.z;
    const int tid  = threadIdx.x;
    const int wave = tid >> 6;
    const int lane = tid & 63;
    const int quad = lane >> 4;
    const int l15  = lane & 15;

    __shared__ u16 Vs[2][128 * 64];  // 2 x 16 KB
    __shared__ u16 Pl[4][16 * 64];   // 8 KB, XOR-swizzled

    auto issueV = [&](int kt, int buf) {
#pragma unroll
        for (int it = 0; it < 4; it++) {
            int cid = it * 256 + tid;
            int c = cid >> 9, p = cid & 511;
            async16(VT + (size_t)((b * 8 + h) * 128 + (p >> 2)) * 2048 + kt +
                        c * 32 + (p & 3) * 8,
                    (char*)Vs[buf] + (it * 256 + wave * 64) * 16);
        }
    };

    bf16x8 qf[2];
    {
        const u16* p = QKV + (size_t)(b * SLEN + q0 + wave * 16 + l15) * 2048 +
                       h * 64 + quad * 8;
        qf[0] = *(const bf16x8*)p;
        qf[1] = *(const bf16x8*)(p + 32);
    }

    const u16* kbase = QKV + (size_t)(b * SLEN) * 2048 + 512 + h * 64 + quad * 8;

    f32x4 o_acc[8];
#pragma unroll
    for (int t = 0; t < 8; t++) o_acc[t] = (f32x4){0.f, 0.f, 0.f, 0.f};
    float m_r[4] = {-1e30f, -1e30f, -1e30f, -1e30f};
    float l_r[4] = {0.f, 0.f, 0.f, 0.f};

    issueV(0, 0);

    for (int ti = 0; ti < SLEN / 64; ti++) {
        __syncthreads();             // implicit vmcnt(0): V(ti) landed
        if (ti + 1 < SLEN / 64) issueV((ti + 1) * 64, (ti + 1) & 1);
        const int buf = ti & 1;
        const int kt = ti * 64;

        // S = Q K^T ; K fragments straight from global
        f32x4 s_acc[4];
#pragma unroll
        for (int t = 0; t < 4; t++) s_acc[t] = (f32x4){0.f, 0.f, 0.f, 0.f};
#pragma unroll
        for (int c = 0; c < 2; c++)
#pragma unroll
            for (int t = 0; t < 4; t++) {
                bf16x8 kb = *(const bf16x8*)(kbase +
                             (size_t)(kt + t * 16 + l15) * 2048 + c * 32);
                s_acc[t] = __builtin_amdgcn_mfma_f32_16x16x32_bf16(qf[c], kb,
                                                                   s_acc[t], 0, 0, 0);
            }

        // online softmax per q-row (exp2 domain)
        float alpha[4];
#pragma unroll
        for (int r = 0; r < 4; r++) {
            float mx = fmaxf(fmaxf(s_acc[0][r], s_acc[1][r]),
                             fmaxf(s_acc[2][r], s_acc[3][r]));
#pragma unroll
            for (int off = 1; off < 16; off <<= 1) mx = fmaxf(mx, __shfl_xor(mx, off, 64));
            float mnew = fmaxf(m_r[r], mx);
            alpha[r] = exp2f(m_r[r] - mnew);
            float ls = 0.f;
            const int row = quad * 4 + r;
#pragma unroll
            for (int t = 0; t < 4; t++) {
                float pv = exp2f(s_acc[t][r] - mnew);
                ls += pv;
                // swizzled u16 index: row*64 + (chunk ^ (row&7))*8 + (l15&7)
                Pl[wave][row * 64 + (((t * 2 + (l15 >> 3)) ^ (row & 7)) << 3) +
                         (l15 & 7)] = f2bf(pv);
            }
#pragma unroll
            for (int off = 1; off < 16; off <<= 1) ls += __shfl_xor(ls, off, 64);
            l_r[r] = l_r[r] * alpha[r] + ls;
            m_r[r] = mnew;
        }
#pragma unroll
        for (int t = 0; t < 8; t++)
#pragma unroll
            for (int r = 0; r < 4; r++) o_acc[t][r] *= alpha[r];

        __asm__ volatile("s_waitcnt lgkmcnt(0)" ::: "memory");  // P writes visible (wave-local)

        // O += P V
#pragma unroll
        for (int c = 0; c < 2; c++) {
            bf16x8 pf = *(const bf16x8*)&Pl[wave][l15 * 64 +
                         ((((c << 2) + quad) ^ (l15 & 7)) << 3)];
#pragma unroll
            for (int t = 0; t < 8; t++) {
                bf16x8 vb = *(const bf16x8*)((const char*)Vs[buf] + c * 8192 +
                             ((t * 16 + l15) * 4 + quad) * 16);
                o_acc[t] = __builtin_amdgcn_mfma_f32_16x16x32_bf16(pf, vb,
                                                                   o_acc[t], 0, 0, 0);
            }
        }
    }

#pragma unroll
    for (int r = 0; r < 4; r++) {
        float inv = ATT_SCALING / l_r[r];
        size_t base = (size_t)(b * SLEN + q0 + wave * 16 + quad * 4 + r) * 1024 + h * 128;
#pragma unroll
        for (int t = 0; t < 8; t++)
            O[base + t * 16 + l15] = f2bf(o_acc[t][r] * inv);
    }
}

// ---------------------------------------------------------------------------
// LN(X + R) * g + be : fp32 in, fp32 + bf16 out (one block per 512-row)
// ---------------------------------------------------------------------------
__global__ __launch_bounds__(256) void addln_kernel(const float* __restrict__ X,
                                                    const float* __restrict__ R,
                                                    const float* __restrict__ g,
                                                    const float* __restrict__ be,
                                                    float* __restrict__ dstf,
                                                    u16* __restrict__ dstb) {
    const int row = blockIdx.x;
    const int tid = threadIdx.x;
    __shared__ float red[256];
    size_t off = (size_t)row * HIDDEN;
    float v0 = X[off + tid] + R[off + tid];
    float v1 = X[off + tid + 256] + R[off + tid + 256];
    red[tid] = v0 + v1;
    __syncthreads();
    for (int s = 128; s > 0; s >>= 1) { if (tid < s) red[tid] += red[tid + s]; __syncthreads(); }
    float mu = red[0] * (1.0f / HIDDEN);
    __syncthreads();
    float d0 = v0 - mu, d1 = v1 - mu;
    red[tid] = d0 * d0 + d1 * d1;
    __syncthreads();
    for (int s = 128; s > 0; s >>= 1) { if (tid < s) red[tid] += red[tid + s]; __syncthreads(); }
    float rstd = rsqrtf(red[0] * (1.0f / HIDDEN) + LN_EPS);
    float o0 = d0 * rstd * g[tid] + be[tid];
    float o1 = d1 * rstd * g[tid + 256] + be[tid + 256];
    dstf[off + tid] = o0;
    dstf[off + tid + 256] = o1;
    dstb[off + tid] = f2bf(o0);
    dstb[off + tid + 256] = f2bf(o1);
}

// ---------------------------------------------------------------------------
extern "C" void kernel_launch(void* const* d_in, const int* in_sizes, int n_in,
                              void* d_out, int out_size, void* d_ws, size_t ws_size,
                              hipStream_t stream) {
    const float* x   = (const float*)d_in[0];
    const float* Wq  = (const float*)d_in[1];
    const float* Wk  = (const float*)d_in[2];
    const float* Wv  = (const float*)d_in[3];
    const float* Wo  = (const float*)d_in[4];
    const float* W1  = (const float*)d_in[5];
    const float* b1  = (const float*)d_in[6];
    const float* W2  = (const float*)d_in[7];
    const float* b2  = (const float*)d_in[8];
    const float* g1  = (const float*)d_in[9];
    const float* be1 = (const float*)d_in[10];
    const float* g2  = (const float*)d_in[11];
    const float* be2 = (const float*)d_in[12];
    float* out = (float*)d_out;

    // Workspace (62.5 MB used):
    //  R1 [ 0..8M)  : A_f32 residual -> F2 fp32
    //  R2 [ 8..16M) : VT (attn)      -> Y_f32
    //  R3 [16..24M) : A_bf (4M)      -> P fp32 (8M)
    //  R4 [24..40M) : QKV bf16 (16M) -> F1 bf16
    //  R5 [40..48M) : AT bf16 (8M)   -> Y_bf (4M)
    //  R6 [48..62M) : bf16 transposed weights
    //  R7 [62..62.5M): xpos table
    const size_t MB = 1u << 20;
    char* w = (char*)d_ws;
    float*  R1f  = (float*)(w);
    u16*    VTg  = (u16*)(w + 8 * MB);
    float*  Yf   = (float*)(w + 8 * MB);
    u16*    A_bf = (u16*)(w + 16 * MB);
    float*  Pf   = (float*)(w + 16 * MB);
    u16*    QKV  = (u16*)(w + 24 * MB);
    u16*    F1   = (u16*)(w + 24 * MB);
    u16*    AT   = (u16*)(w + 40 * MB);
    u16*    Y_bf = (u16*)(w + 40 * MB);
    float2* xtab = (float2*)(w + 62 * MB);

    cvt_x<<<MROWS * HIDDEN / 256, 256, 0, stream>>>(x, R1f, A_bf);
    xpos_table<<<256, 256, 0, stream>>>(xtab);

    for (int l = 0; l < LAYERS; l++) {
        u16* WqkvT = (u16*)(w + 48 * MB + (size_t)l * 2 * MB);
        u16* WoT   = (u16*)(w + 52 * MB + (size_t)l * 1 * MB);
        u16* W1T   = (u16*)(w + 54 * MB + (size_t)l * 2 * MB);
        u16* W2T   = (u16*)(w + 58 * MB + (size_t)l * 2 * MB);
        wtrans<<<dim3(16, 16), 256, 0, stream>>>(Wq + (size_t)l * 512 * 512,  WqkvT,              512, 512);
        wtrans<<<dim3(16, 16), 256, 0, stream>>>(Wk + (size_t)l * 512 * 512,  WqkvT + 512 * 512,  512, 512);
        wtrans<<<dim3(32, 16), 256, 0, stream>>>(Wv + (size_t)l * 512 * 1024, WqkvT + 1024 * 512, 512, 1024);
        wtrans<<<dim3(16, 32), 256, 0, stream>>>(Wo + (size_t)l * 1024 * 512, WoT,                1024, 512);
        wtrans<<<dim3(64, 16), 256, 0, stream>>>(W1 + (size_t)l * 512 * 2048, W1T,                512, 2048);
        wtrans<<<dim3(16, 64), 256, 0, stream>>>(W2 + (size_t)l * 2048 * 512, W2T,                2048, 512);
    }

    for (int l = 0; l < LAYERS; l++) {
        u16* WqkvT = (u16*)(w + 48 * MB + (size_t)l * 2 * MB);
        u16* WoT   = (u16*)(w + 52 * MB + (size_t)l * 1 * MB);
        u16* W1T   = (u16*)(w + 54 * MB + (size_t)l * 2 * MB);
        u16* W2T   = (u16*)(w + 58 * MB + (size_t)l * 2 * MB);
        const float* b1_l  = b1 + (size_t)l * FFN_DIM;
        const float* b2_l  = b2 + (size_t)l * HIDDEN;
        const float* g1_l  = g1 + (size_t)l * HIDDEN;
        const float* be1_l = be1 + (size_t)l * HIDDEN;
        const float* g2_l  = g2 + (size_t)l * HIDDEN;
        const float* be2_l = be2 + (size_t)l * HIDDEN;

        // QKV = A_bf @ [Wq|Wk|Wv]  (bf16 out), 512 blocks
        gemm_mfma<128, 128, 2, 0, 0, 0><<<dim3(16, 32), 256, 0, stream>>>(
            A_bf, WqkvT, nullptr, QKV, MROWS, 2048, 512);

        xpos_kernel<<<4096, 256, 0, stream>>>(QKV, xtab);
        vtrans<<<dim3(32, 2, 16), 256, 0, stream>>>(QKV, VTg);

        flash_attn_mfma<<<dim3(32, 8, 2), 256, 0, stream>>>(QKV, VTg, AT);

        // P = AT @ Wo (fp32 out), 64x64 tiles -> 512 blocks
        gemm_mfma<64, 64, 2, 1, 0, 0><<<dim3(8, 64), 256, 0, stream>>>(
            AT, WoT, nullptr, Pf, MROWS, 512, 1024);

        // Y = LN(A + P)
        addln_kernel<<<MROWS, 256, 0, stream>>>(R1f, Pf, g1_l, be1_l, Yf, Y_bf);

        // F1 = relu(Y @ W1 + b1) (bf16 out), 512 blocks
        gemm_mfma<128, 128, 2, 0, 1, 1><<<dim3(16, 32), 256, 0, stream>>>(
            Y_bf, W1T, b1_l, F1, MROWS, 2048, 512);

        // F2 = F1 @ W2 + b2 (fp32 out), 64x64 tiles -> 512 blocks
        gemm_mfma<64, 64, 2, 1, 1, 0><<<dim3(8, 64), 256, 0, stream>>>(
            F1, W2T, b2_l, R1f, MROWS, 512, 2048);

        // x_next = LN(Y + F2)
        float* dstf = (l == LAYERS - 1) ? out : R1f;
        addln_kernel<<<MROWS, 256, 0, stream>>>(Yf, R1f, g2_l, be2_l, dstf, A_bf);
    }
}

// Round 7
// 497.001 us; speedup vs baseline: 1.1896x; 1.1896x over previous
//
#include <hip/hip_runtime.h>
#include <math.h>

#define LAYERS 2
#define HIDDEN 512
#define FFN_DIM 2048
#define HEADS 8
#define SLEN 2048
#define BSZ 2
#define MROWS 4096
#define ATT_SCALING 0.125f
#define LN_EPS 1e-5f
#define SCALE_BASE 512.0f
#define LOG2E 1.4426950408889634f

typedef unsigned short u16;
typedef unsigned int u32;
typedef __attribute__((ext_vector_type(8))) short bf16x8;   // 8 bf16 = 4 VGPR
typedef __attribute__((ext_vector_type(4))) float f32x4;

__device__ __forceinline__ float bf2f(u16 u) {
    union { u32 i; float f; } v; v.i = ((u32)u) << 16; return v.f;
}
__device__ __forceinline__ u16 f2bf(float f) {
    union { float f; u32 i; } v; v.f = f;
    u32 r = v.i + 0x7FFFu + ((v.i >> 16) & 1u);   // RNE
    return (u16)(r >> 16);
}
__device__ __forceinline__ void async16(const void* g, void* l) {
    __builtin_amdgcn_global_load_lds((const __attribute__((address_space(1))) void*)g,
                                     (__attribute__((address_space(3))) void*)l, 16, 0, 0);
}

// ---------------------------------------------------------------------------
// fp32 [K][N] -> bf16 [N][K] transpose (weights prep)
// ---------------------------------------------------------------------------
__global__ __launch_bounds__(256) void wtrans(const float* __restrict__ in,
                                              u16* __restrict__ out,
                                              int K, int N) {
    __shared__ float t[32][33];
    int tx = threadIdx.x & 31, ty = threadIdx.x >> 5;       // 32 x 8
    int k0 = blockIdx.y * 32, n0 = blockIdx.x * 32;
#pragma unroll
    for (int i = 0; i < 4; i++)
        t[ty + 8 * i][tx] = in[(size_t)(k0 + ty + 8 * i) * N + n0 + tx];
    __syncthreads();
#pragma unroll
    for (int i = 0; i < 4; i++)
        out[(size_t)(n0 + ty + 8 * i) * K + k0 + tx] = f2bf(t[tx][ty + 8 * i]);
}

// ---------------------------------------------------------------------------
// x fp32 -> residual fp32 copy + bf16 copy
// ---------------------------------------------------------------------------
__global__ __launch_bounds__(256) void cvt_x(const float* __restrict__ x,
                                             float* __restrict__ Af,
                                             u16* __restrict__ Ab) {
    int i = blockIdx.x * 256 + threadIdx.x;
    float v = x[i];
    Af[i] = v;
    Ab[i] = f2bf(v);
}

// ---------------------------------------------------------------------------
// xPos cos/sin table: tab[s*32+j] = (cos*scale, sin*scale)
// ---------------------------------------------------------------------------
__global__ __launch_bounds__(256) void xpos_table(float2* __restrict__ tab) {
    int idx = blockIdx.x * 256 + threadIdx.x;   // 2048*32 = 65536
    int j = idx & 31;
    int s = idx >> 5;
    float base = (2.0f * j + 0.4f * 64.0f) / (1.4f * 64.0f);
    float pos = (float)(s - 1024);
    float scale = powf(base, pos / SCALE_BASE);
    float inv_freq = powf(10000.0f, -(float)j / 32.0f);
    float ang = (float)s * inv_freq;
    tab[idx] = make_float2(cosf(ang) * scale, sinf(ang) * scale);
}

// ---------------------------------------------------------------------------
// xPos applied in-place to Q (cols h*64+..) and K (cols 512+h*64+..) of QKV
// bf16, packed u32 accesses. Q additionally scaled by LOG2E (exp2 softmax).
// ---------------------------------------------------------------------------
__global__ __launch_bounds__(256) void xpos_kernel(u16* __restrict__ QKV,
                                                   const float2* __restrict__ tab) {
    int idx = blockIdx.x * 256 + threadIdx.x;   // 2^20
    int j = idx & 31;
    int h = (idx >> 5) & 7;
    int s = (idx >> 8) & 2047;
    int b = idx >> 19;

    float2 cssn = tab[s * 32 + j];
    float cs = cssn.x, sn = cssn.y;

    size_t off = (size_t)(b * SLEN + s) * 2048 + h * 64 + 2 * j;
    u32* pq = (u32*)(QKV + off);
    u32* pk = (u32*)(QKV + off + 512);

    u32 qv = *pq;
    float q0 = bf2f((u16)(qv & 0xffff)), q1 = bf2f((u16)(qv >> 16));
    *pq = (u32)f2bf((q0 * cs - q1 * sn) * LOG2E) |
          ((u32)f2bf((q1 * cs + q0 * sn) * LOG2E) << 16);

    u32 kv = *pk;
    float k0 = bf2f((u16)(kv & 0xffff)), k1 = bf2f((u16)(kv >> 16));
    *pk = (u32)f2bf(k0 * cs - k1 * sn) | ((u32)f2bf(k1 * cs + k0 * sn) << 16);
}

// ---------------------------------------------------------------------------
// V section of QKV -> VT[(b*8+h)*128 + v][s]  (bf16 -> bf16 transpose)
// ---------------------------------------------------------------------------
__global__ __launch_bounds__(256) void vtrans(const u16* __restrict__ QKV,
                                              u16* __restrict__ VT) {
    __shared__ u16 t[64][65];
    int b = blockIdx.z >> 3, h = blockIdx.z & 7;
    int s0 = blockIdx.x * 64, v0 = blockIdx.y * 64;
    int tid = threadIdx.x;
#pragma unroll
    for (int i = 0; i < 16; i++) {
        int e = tid + i * 256; int r = e >> 6, c = e & 63;      // r: s, c: v
        t[r][c] = QKV[(size_t)(b * SLEN + s0 + r) * 2048 + 1024 + h * 128 + v0 + c];
    }
    __syncthreads();
#pragma unroll
    for (int i = 0; i < 16; i++) {
        int e = tid + i * 256; int r = e >> 6, c = e & 63;      // r: v, c: s
        VT[(size_t)((b * 8 + h) * 128 + v0 + r) * 2048 + s0 + c] = t[c][r];
    }
}

// ---------------------------------------------------------------------------
// MFMA GEMM, software-pipelined (unchanged from round 4).
// ---------------------------------------------------------------------------
template <int BM, int BN, int WM, int OUTF32, int BIAS, int RELU>
__global__ __launch_bounds__(256) void gemm_mfma(const u16* __restrict__ A,
                                                 const u16* __restrict__ WT,
                                                 const float* __restrict__ bias,
                                                 void* __restrict__ Cout,
                                                 int M, int N, int K) {
    constexpr int WN = 4 / WM;
    constexpr int AM = BM / (WM * 16);
    constexpr int AN = BN / (WN * 16);
    constexpr int AIT = BM / 64;
    constexpr int BIT = BN / 64;

    __shared__ u16 As[2][BM * 32];
    __shared__ u16 Bs[2][BN * 32];

    const int tid  = threadIdx.x;
    const int wave = tid >> 6;
    const int lane = tid & 63;
    const int quad = lane >> 4;
    const int l15  = lane & 15;
    const int wm = wave % WM;
    const int wn = wave / WM;

    const int tm = blockIdx.y * BM;
    const int tn = blockIdx.x * BN;

    auto issue = [&](int kt, int buf) {
#pragma unroll
        for (int it = 0; it < AIT; it++) {
            int cid = it * 256 + tid;
            async16(A + (size_t)(tm + (cid >> 2)) * K + kt + (cid & 3) * 8,
                    (char*)As[buf] + (it * 256 + wave * 64) * 16);
        }
#pragma unroll
        for (int it = 0; it < BIT; it++) {
            int cid = it * 256 + tid;
            async16(WT + (size_t)(tn + (cid >> 2)) * K + kt + (cid & 3) * 8,
                    (char*)Bs[buf] + (it * 256 + wave * 64) * 16);
        }
    };

    f32x4 acc[AM][AN];
#pragma unroll
    for (int i = 0; i < AM; i++)
#pragma unroll
        for (int j = 0; j < AN; j++) acc[i][j] = (f32x4){0.f, 0.f, 0.f, 0.f};

    const int nk = K >> 5;
    issue(0, 0);

    for (int t = 0; t < nk; t++) {
        __syncthreads();             // implicit vmcnt(0) drain: loads(t) done
        if (t + 1 < nk) issue((t + 1) << 5, (t + 1) & 1);
        const int buf = t & 1;

        bf16x8 af[AM], bfr[AN];
#pragma unroll
        for (int i = 0; i < AM; i++)
            af[i] = *(const bf16x8*)((const char*)As[buf] +
                     ((wm * (AM * 16) + i * 16 + l15) * 4 + quad) * 16);
#pragma unroll
        for (int j = 0; j < AN; j++)
            bfr[j] = *(const bf16x8*)((const char*)Bs[buf] +
                     ((wn * (AN * 16) + j * 16 + l15) * 4 + quad) * 16);
#pragma unroll
        for (int i = 0; i < AM; i++)
#pragma unroll
            for (int j = 0; j < AN; j++)
                acc[i][j] = __builtin_amdgcn_mfma_f32_16x16x32_bf16(af[i], bfr[j],
                                                                    acc[i][j], 0, 0, 0);
    }

#pragma unroll
    for (int i = 0; i < AM; i++) {
#pragma unroll
        for (int j = 0; j < AN; j++) {
            int col = tn + wn * (AN * 16) + j * 16 + l15;
            float bv = BIAS ? bias[col] : 0.0f;
#pragma unroll
            for (int r = 0; r < 4; r++) {
                int row = tm + wm * (AM * 16) + i * 16 + quad * 4 + r;
                float v = acc[i][j][r] + bv;
                if (RELU) v = fmaxf(v, 0.0f);
                if (OUTF32) ((float*)Cout)[(size_t)row * N + col] = v;
                else        ((u16*)Cout)[(size_t)row * N + col] = f2bf(v);
            }
        }
    }
}

// ---------------------------------------------------------------------------
// MFMA flash attention v3 (fixed), 2-way split-K.
//  - S computed TRANSPOSED (A=K, B=Q): softmax state lives per-lane at q=l15.
//  - o_acc rows are q=quad*4+r (PV C/D layout)  =>  alpha must be broadcast
//    from lane l15'=quad*4+r before rescaling (the r6 bug).
//  - P never touches LDS: PV A-fragment gathered via __shfl.
//  - Unnormalized partial O (bf16) + (m,l); combine kernel merges splits.
// ---------------------------------------------------------------------------
__global__ __launch_bounds__(256, 3) void flash_attn_mfma(const u16* __restrict__ QKV,
                                                          const u16* __restrict__ VT,
                                                          u16* __restrict__ OP0,
                                                          u16* __restrict__ OP1,
                                                          float2* __restrict__ ML) {
    const int q0 = blockIdx.x * 64;
    const int h  = blockIdx.y;
    const int bz = blockIdx.z;           // b*2 + split
    const int b  = bz >> 1;
    const int split = bz & 1;
    const int tid  = threadIdx.x;
    const int wave = tid >> 6;
    const int lane = tid & 63;
    const int quad = lane >> 4;
    const int l15  = lane & 15;

    __shared__ u16 Ks[2][64 * 64];   // 2 x 8 KB
    __shared__ u16 Vs[2][128 * 64];  // 2 x 16 KB   (48 KB total)

    auto issueKV = [&](int kt, int buf) {
#pragma unroll
        for (int it = 0; it < 2; it++) {
            int cid = it * 256 + tid;
            int c = cid >> 8, p = cid & 255;
            async16(QKV + (size_t)(b * SLEN + kt + (p >> 2)) * 2048 + 512 + h * 64 +
                        c * 32 + (p & 3) * 8,
                    (char*)Ks[buf] + (it * 256 + wave * 64) * 16);
        }
#pragma unroll
        for (int it = 0; it < 4; it++) {
            int cid = it * 256 + tid;
            int c = cid >> 9, p = cid & 511;
            async16(VT + (size_t)((b * 8 + h) * 128 + (p >> 2)) * 2048 + kt +
                        c * 32 + (p & 3) * 8,
                    (char*)Vs[buf] + (it * 256 + wave * 64) * 16);
        }
    };

    bf16x8 qf[2];
    {
        const u16* p = QKV + (size_t)(b * SLEN + q0 + wave * 16 + l15) * 2048 +
                       h * 64 + quad * 8;
        qf[0] = *(const bf16x8*)p;
        qf[1] = *(const bf16x8*)(p + 32);
    }

    f32x4 o_acc[8];
#pragma unroll
    for (int t = 0; t < 8; t++) o_acc[t] = (f32x4){0.f, 0.f, 0.f, 0.f};
    float m = -1e30f, l = 0.f;           // per-lane: q = l15 (replicated x4 quads)

    const int kb0 = split * 1024;
    issueKV(kb0, 0);

    for (int ti = 0; ti < 16; ti++) {
        __syncthreads();                 // implicit vmcnt(0): tiles(ti) landed
        if (ti + 1 < 16) issueKV(kb0 + (ti + 1) * 64, (ti + 1) & 1);
        const int buf = ti & 1;

        // S^T: D[key][q], key = t*16 + quad*4 + r, q = l15
        f32x4 st[4];
#pragma unroll
        for (int t = 0; t < 4; t++) st[t] = (f32x4){0.f, 0.f, 0.f, 0.f};
#pragma unroll
        for (int c = 0; c < 2; c++)
#pragma unroll
            for (int t = 0; t < 4; t++) {
                bf16x8 kb = *(const bf16x8*)((const char*)Ks[buf] + c * 4096 +
                             ((t * 16 + l15) * 4 + quad) * 16);
                st[t] = __builtin_amdgcn_mfma_f32_16x16x32_bf16(kb, qf[c],
                                                                st[t], 0, 0, 0);
            }

        // softmax over keys (state at q=l15): in-register over 16 + 2 shfls
        float mx = -1e30f;
#pragma unroll
        for (int t = 0; t < 4; t++)
#pragma unroll
            for (int r = 0; r < 4; r++) mx = fmaxf(mx, st[t][r]);
        mx = fmaxf(mx, __shfl_xor(mx, 16, 64));
        mx = fmaxf(mx, __shfl_xor(mx, 32, 64));
        float mnew = fmaxf(m, mx);
        float alpha = exp2f(m - mnew);

        float pv[4][4];
        float ls = 0.f;
#pragma unroll
        for (int t = 0; t < 4; t++)
#pragma unroll
            for (int r = 0; r < 4; r++) {
                pv[t][r] = exp2f(st[t][r] - mnew);
                ls += pv[t][r];
            }
        ls += __shfl_xor(ls, 16, 64);
        ls += __shfl_xor(ls, 32, 64);
        l = l * alpha + ls;
        m = mnew;

        // broadcast alpha to accumulator layout: o_acc rows are q=quad*4+r,
        // alpha lives at lanes with l15' = q (replicated across quads)
        float a4[4];
#pragma unroll
        for (int r = 0; r < 4; r++)
            a4[r] = __shfl(alpha, quad * 16 + quad * 4 + r, 64);
#pragma unroll
        for (int t = 0; t < 8; t++)
#pragma unroll
            for (int r = 0; r < 4; r++) o_acc[t][r] *= a4[r];

        // pack exp'd scores to bf16 pairs: pp[t][pr] = keys (16t+4quad+2pr, +1)
        u32 pp[4][2];
#pragma unroll
        for (int t = 0; t < 4; t++)
#pragma unroll
            for (int pr = 0; pr < 2; pr++)
                pp[t][pr] = (u32)f2bf(pv[t][2 * pr]) |
                            ((u32)f2bf(pv[t][2 * pr + 1]) << 16);

        // PV: gather P A-fragment via shfl (lane needs q=l15, keys quad*8..+7)
#pragma unroll
        for (int c = 0; c < 2; c++) {
            union { u32 u[4]; bf16x8 v; } pu;
#pragma unroll
            for (int j2 = 0; j2 < 4; j2++) {
                int src = (2 * (quad & 1) + (j2 >> 1)) * 16 + l15;
                u32 g0 = (u32)__shfl((int)pp[2 * c][j2 & 1], src, 64);
                u32 g1 = (u32)__shfl((int)pp[2 * c + 1][j2 & 1], src, 64);
                pu.u[j2] = (quad & 2) ? g1 : g0;
            }
            bf16x8 pf = pu.v;
#pragma unroll
            for (int t = 0; t < 8; t++) {
                bf16x8 vb = *(const bf16x8*)((const char*)Vs[buf] + c * 8192 +
                             ((t * 16 + l15) * 4 + quad) * 16);
                o_acc[t] = __builtin_amdgcn_mfma_f32_16x16x32_bf16(pf, vb,
                                                                   o_acc[t], 0, 0, 0);
            }
        }
    }

    // epilogue: unnormalized partial O + (m,l)
    if (quad == 0)
        ML[((size_t)(split * 2 + b) * 8 + h) * 2048 + q0 + wave * 16 + l15] =
            make_float2(m, l);

    u16* OP = split ? OP1 : OP0;
#pragma unroll
    for (int r = 0; r < 4; r++) {
        size_t base = ((size_t)(b * SLEN + q0 + wave * 16 + quad * 4 + r)) * 1024 +
                      h * 128;
#pragma unroll
        for (int t = 0; t < 8; t++)
            OP[base + t * 16 + l15] = f2bf(o_acc[t][r]);
    }
}

// ---------------------------------------------------------------------------
// Merge the two split-K partials: out = SCALING * (O0*w0 + O1*w1) / L
// ---------------------------------------------------------------------------
__global__ __launch_bounds__(256) void attn_combine(const u16* __restrict__ P0,
                                                    const u16* __restrict__ P1,
                                                    const float2* __restrict__ ML,
                                                    u16* __restrict__ AT) {
    int idx = blockIdx.x * 256 + threadIdx.x;   // 4096*1024
    int hv = idx & 1023;
    int row = idx >> 10;                        // b*2048 + q
    int h = hv >> 7;
    int b = row >> 11, q = row & 2047;
    float2 ml0 = ML[((size_t)(0 + b) * 8 + h) * 2048 + q];
    float2 ml1 = ML[((size_t)(2 + b) * 8 + h) * 2048 + q];
    float M = fmaxf(ml0.x, ml1.x);
    float w0 = exp2f(ml0.x - M), w1 = exp2f(ml1.x - M);
    float L = ml0.y * w0 + ml1.y * w1;
    float o = bf2f(P0[idx]) * w0 + bf2f(P1[idx]) * w1;
    AT[idx] = f2bf(ATT_SCALING * o / L);
}

// ---------------------------------------------------------------------------
// LN(X + R) * g + be : fp32 in, fp32 + bf16 out (one block per 512-row)
// ---------------------------------------------------------------------------
__global__ __launch_bounds__(256) void addln_kernel(const float* __restrict__ X,
                                                    const float* __restrict__ R,
                                                    const float* __restrict__ g,
                                                    const float* __restrict__ be,
                                                    float* __restrict__ dstf,
                                                    u16* __restrict__ dstb) {
    const int row = blockIdx.x;
    const int tid = threadIdx.x;
    __shared__ float red[256];
    size_t off = (size_t)row * HIDDEN;
    float v0 = X[off + tid] + R[off + tid];
    float v1 = X[off + tid + 256] + R[off + tid + 256];
    red[tid] = v0 + v1;
    __syncthreads();
    for (int s = 128; s > 0; s >>= 1) { if (tid < s) red[tid] += red[tid + s]; __syncthreads(); }
    float mu = red[0] * (1.0f / HIDDEN);
    __syncthreads();
    float d0 = v0 - mu, d1 = v1 - mu;
    red[tid] = d0 * d0 + d1 * d1;
    __syncthreads();
    for (int s = 128; s > 0; s >>= 1) { if (tid < s) red[tid] += red[tid + s]; __syncthreads(); }
    float rstd = rsqrtf(red[0] * (1.0f / HIDDEN) + LN_EPS);
    float o0 = d0 * rstd * g[tid] + be[tid];
    float o1 = d1 * rstd * g[tid + 256] + be[tid + 256];
    dstf[off + tid] = o0;
    dstf[off + tid + 256] = o1;
    dstb[off + tid] = f2bf(o0);
    dstb[off + tid + 256] = f2bf(o1);
}

// ---------------------------------------------------------------------------
extern "C" void kernel_launch(void* const* d_in, const int* in_sizes, int n_in,
                              void* d_out, int out_size, void* d_ws, size_t ws_size,
                              hipStream_t stream) {
    const float* x   = (const float*)d_in[0];
    const float* Wq  = (const float*)d_in[1];
    const float* Wk  = (const float*)d_in[2];
    const float* Wv  = (const float*)d_in[3];
    const float* Wo  = (const float*)d_in[4];
    const float* W1  = (const float*)d_in[5];
    const float* b1  = (const float*)d_in[6];
    const float* W2  = (const float*)d_in[7];
    const float* b2  = (const float*)d_in[8];
    const float* g1  = (const float*)d_in[9];
    const float* be1 = (const float*)d_in[10];
    const float* g2  = (const float*)d_in[11];
    const float* be2 = (const float*)d_in[12];
    float* out = (float*)d_out;

    // Workspace (63 MB used):
    //  R1 [ 0..8M)  : A_f32 residual -> F2 fp32
    //  R2 [ 8..16M) : VT (attn)      -> Y_f32
    //  R3 [16..24M) : A_bf (4M)      -> O-partial split1 (8M) -> P fp32 (8M)
    //  R4 [24..40M) : QKV bf16 (16M) -> F1 bf16
    //  R5 [40..48M) : O-partial split0 / AT bf16 (8M) -> Y_bf (4M)
    //  R6 [48..62M) : bf16 transposed weights
    //  R7 [62..62.5M): xpos table ; [62.5..63M): attention (m,l)
    const size_t MB = 1u << 20;
    char* w = (char*)d_ws;
    float*  R1f  = (float*)(w);
    u16*    VTg  = (u16*)(w + 8 * MB);
    float*  Yf   = (float*)(w + 8 * MB);
    u16*    A_bf = (u16*)(w + 16 * MB);
    u16*    OP1  = (u16*)(w + 16 * MB);
    float*  Pf   = (float*)(w + 16 * MB);
    u16*    QKV  = (u16*)(w + 24 * MB);
    u16*    F1   = (u16*)(w + 24 * MB);
    u16*    OP0  = (u16*)(w + 40 * MB);
    u16*    AT   = (u16*)(w + 40 * MB);
    u16*    Y_bf = (u16*)(w + 40 * MB);
    float2* xtab = (float2*)(w + 62 * MB);
    float2* ML   = (float2*)(w + 62 * MB + 512 * 1024);

    cvt_x<<<MROWS * HIDDEN / 256, 256, 0, stream>>>(x, R1f, A_bf);
    xpos_table<<<256, 256, 0, stream>>>(xtab);

    for (int l = 0; l < LAYERS; l++) {
        u16* WqkvT = (u16*)(w + 48 * MB + (size_t)l * 2 * MB);
        u16* WoT   = (u16*)(w + 52 * MB + (size_t)l * 1 * MB);
        u16* W1T   = (u16*)(w + 54 * MB + (size_t)l * 2 * MB);
        u16* W2T   = (u16*)(w + 58 * MB + (size_t)l * 2 * MB);
        wtrans<<<dim3(16, 16), 256, 0, stream>>>(Wq + (size_t)l * 512 * 512,  WqkvT,              512, 512);
        wtrans<<<dim3(16, 16), 256, 0, stream>>>(Wk + (size_t)l * 512 * 512,  WqkvT + 512 * 512,  512, 512);
        wtrans<<<dim3(32, 16), 256, 0, stream>>>(Wv + (size_t)l * 512 * 1024, WqkvT + 1024 * 512, 512, 1024);
        wtrans<<<dim3(16, 32), 256, 0, stream>>>(Wo + (size_t)l * 1024 * 512, WoT,                1024, 512);
        wtrans<<<dim3(64, 16), 256, 0, stream>>>(W1 + (size_t)l * 512 * 2048, W1T,                512, 2048);
        wtrans<<<dim3(16, 64), 256, 0, stream>>>(W2 + (size_t)l * 2048 * 512, W2T,                2048, 512);
    }

    for (int l = 0; l < LAYERS; l++) {
        u16* WqkvT = (u16*)(w + 48 * MB + (size_t)l * 2 * MB);
        u16* WoT   = (u16*)(w + 52 * MB + (size_t)l * 1 * MB);
        u16* W1T   = (u16*)(w + 54 * MB + (size_t)l * 2 * MB);
        u16* W2T   = (u16*)(w + 58 * MB + (size_t)l * 2 * MB);
        const float* b1_l  = b1 + (size_t)l * FFN_DIM;
        const float* b2_l  = b2 + (size_t)l * HIDDEN;
        const float* g1_l  = g1 + (size_t)l * HIDDEN;
        const float* be1_l = be1 + (size_t)l * HIDDEN;
        const float* g2_l  = g2 + (size_t)l * HIDDEN;
        const float* be2_l = be2 + (size_t)l * HIDDEN;

        // QKV = A_bf @ [Wq|Wk|Wv]  (bf16 out), 512 blocks
        gemm_mfma<128, 128, 2, 0, 0, 0><<<dim3(16, 32), 256, 0, stream>>>(
            A_bf, WqkvT, nullptr, QKV, MROWS, 2048, 512);

        xpos_kernel<<<4096, 256, 0, stream>>>(QKV, xtab);
        vtrans<<<dim3(32, 2, 16), 256, 0, stream>>>(QKV, VTg);

        // flash attention, 2-way split-K: z = b*2 + split
        flash_attn_mfma<<<dim3(32, 8, 4), 256, 0, stream>>>(QKV, VTg, OP0, OP1, ML);
        attn_combine<<<MROWS * 1024 / 256, 256, 0, stream>>>(OP0, OP1, ML, AT);

        // P = AT @ Wo (fp32 out), 64x64 tiles -> 512 blocks
        gemm_mfma<64, 64, 2, 1, 0, 0><<<dim3(8, 64), 256, 0, stream>>>(
            AT, WoT, nullptr, Pf, MROWS, 512, 1024);

        // Y = LN(A + P)
        addln_kernel<<<MROWS, 256, 0, stream>>>(R1f, Pf, g1_l, be1_l, Yf, Y_bf);

        // F1 = relu(Y @ W1 + b1) (bf16 out), 512 blocks
        gemm_mfma<128, 128, 2, 0, 1, 1><<<dim3(16, 32), 256, 0, stream>>>(
            Y_bf, W1T, b1_l, F1, MROWS, 2048, 512);

        // F2 = F1 @ W2 + b2 (fp32 out), 64x64 tiles -> 512 blocks
        gemm_mfma<64, 64, 2, 1, 1, 0><<<dim3(8, 64), 256, 0, stream>>>(
            F1, W2T, b2_l, R1f, MROWS, 512, 2048);

        // x_next = LN(Y + F2)
        float* dstf = (l == LAYERS - 1) ? out : R1f;
        addln_kernel<<<MROWS, 256, 0, stream>>>(Yf, R1f, g2_l, be2_l, dstf, A_bf);
    }
}

// Round 8
// 471.525 us; speedup vs baseline: 1.2539x; 1.0540x over previous
//
#include <hip/hip_runtime.h>
#include <hip/hip_bf16.h>
#include <math.h>

#define LAYERS 2
#define HIDDEN 512
#define FFN_DIM 2048
#define HEADS 8
#define SLEN 2048
#define BSZ 2
#define MROWS 4096
#define ATT_SCALING 0.125f
#define LN_EPS 1e-5f
#define SCALE_BASE 512.0f
#define LOG2E 1.4426950408889634f

typedef unsigned short u16;
typedef unsigned int u32;
typedef __attribute__((ext_vector_type(8))) short bf16x8;   // 8 bf16 = 4 VGPR
typedef __attribute__((ext_vector_type(4))) float f32x4;

__device__ __forceinline__ float bf2f(u16 u) {
    union { u32 i; float f; } v; v.i = ((u32)u) << 16; return v.f;
}
__device__ __forceinline__ u16 f2bf(float f) {
    union { float f; u32 i; } v; v.f = f;
    u32 r = v.i + 0x7FFFu + ((v.i >> 16) & 1u);   // RNE
    return (u16)(r >> 16);
}
__device__ __forceinline__ u32 pk2bf(float a, float b) {   // packed RNE cvt
    union { __hip_bfloat162 h; u32 u; } v;
    v.h = __float22bfloat162_rn(make_float2(a, b));
    return v.u;
}
__device__ __forceinline__ void async16(const void* g, void* l) {
    __builtin_amdgcn_global_load_lds((const __attribute__((address_space(1))) void*)g,
                                     (__attribute__((address_space(3))) void*)l, 16, 0, 0);
}

// ---------------------------------------------------------------------------
// fp32 [K][N] -> bf16 [N][K] transpose (weights prep)
// ---------------------------------------------------------------------------
__global__ __launch_bounds__(256) void wtrans(const float* __restrict__ in,
                                              u16* __restrict__ out,
                                              int K, int N) {
    __shared__ float t[32][33];
    int tx = threadIdx.x & 31, ty = threadIdx.x >> 5;       // 32 x 8
    int k0 = blockIdx.y * 32, n0 = blockIdx.x * 32;
#pragma unroll
    for (int i = 0; i < 4; i++)
        t[ty + 8 * i][tx] = in[(size_t)(k0 + ty + 8 * i) * N + n0 + tx];
    __syncthreads();
#pragma unroll
    for (int i = 0; i < 4; i++)
        out[(size_t)(n0 + ty + 8 * i) * K + k0 + tx] = f2bf(t[tx][ty + 8 * i]);
}

// ---------------------------------------------------------------------------
// x fp32 -> residual fp32 copy + bf16 copy
// ---------------------------------------------------------------------------
__global__ __launch_bounds__(256) void cvt_x(const float* __restrict__ x,
                                             float* __restrict__ Af,
                                             u16* __restrict__ Ab) {
    int i = blockIdx.x * 256 + threadIdx.x;
    float v = x[i];
    Af[i] = v;
    Ab[i] = f2bf(v);
}

// ---------------------------------------------------------------------------
// xPos cos/sin table: tab[s*32+j] = (cos*scale, sin*scale)
// ---------------------------------------------------------------------------
__global__ __launch_bounds__(256) void xpos_table(float2* __restrict__ tab) {
    int idx = blockIdx.x * 256 + threadIdx.x;   // 2048*32 = 65536
    int j = idx & 31;
    int s = idx >> 5;
    float base = (2.0f * j + 0.4f * 64.0f) / (1.4f * 64.0f);
    float pos = (float)(s - 1024);
    float scale = powf(base, pos / SCALE_BASE);
    float inv_freq = powf(10000.0f, -(float)j / 32.0f);
    float ang = (float)s * inv_freq;
    tab[idx] = make_float2(cosf(ang) * scale, sinf(ang) * scale);
}

// ---------------------------------------------------------------------------
// xPos applied in-place to Q (cols h*64+..) and K (cols 512+h*64+..) of QKV
// bf16, packed u32 accesses. Q additionally scaled by LOG2E (exp2 softmax).
// ---------------------------------------------------------------------------
__global__ __launch_bounds__(256) void xpos_kernel(u16* __restrict__ QKV,
                                                   const float2* __restrict__ tab) {
    int idx = blockIdx.x * 256 + threadIdx.x;   // 2^20
    int j = idx & 31;
    int h = (idx >> 5) & 7;
    int s = (idx >> 8) & 2047;
    int b = idx >> 19;

    float2 cssn = tab[s * 32 + j];
    float cs = cssn.x, sn = cssn.y;

    size_t off = (size_t)(b * SLEN + s) * 2048 + h * 64 + 2 * j;
    u32* pq = (u32*)(QKV + off);
    u32* pk = (u32*)(QKV + off + 512);

    u32 qv = *pq;
    float q0 = bf2f((u16)(qv & 0xffff)), q1 = bf2f((u16)(qv >> 16));
    *pq = pk2bf((q0 * cs - q1 * sn) * LOG2E, (q1 * cs + q0 * sn) * LOG2E);

    u32 kv = *pk;
    float k0 = bf2f((u16)(kv & 0xffff)), k1 = bf2f((u16)(kv >> 16));
    *pk = pk2bf(k0 * cs - k1 * sn, k1 * cs + k0 * sn);
}

// ---------------------------------------------------------------------------
// V section of QKV -> VT[(b*8+h)*128 + v][s]  (bf16 -> bf16 transpose)
// ---------------------------------------------------------------------------
__global__ __launch_bounds__(256) void vtrans(const u16* __restrict__ QKV,
                                              u16* __restrict__ VT) {
    __shared__ u16 t[64][65];
    int b = blockIdx.z >> 3, h = blockIdx.z & 7;
    int s0 = blockIdx.x * 64, v0 = blockIdx.y * 64;
    int tid = threadIdx.x;
#pragma unroll
    for (int i = 0; i < 16; i++) {
        int e = tid + i * 256; int r = e >> 6, c = e & 63;      // r: s, c: v
        t[r][c] = QKV[(size_t)(b * SLEN + s0 + r) * 2048 + 1024 + h * 128 + v0 + c];
    }
    __syncthreads();
#pragma unroll
    for (int i = 0; i < 16; i++) {
        int e = tid + i * 256; int r = e >> 6, c = e & 63;      // r: v, c: s
        VT[(size_t)((b * 8 + h) * 128 + v0 + r) * 2048 + s0 + c] = t[c][r];
    }
}

// ---------------------------------------------------------------------------
// MFMA GEMM, software-pipelined (unchanged from round 4).
// ---------------------------------------------------------------------------
template <int BM, int BN, int WM, int OUTF32, int BIAS, int RELU>
__global__ __launch_bounds__(256) void gemm_mfma(const u16* __restrict__ A,
                                                 const u16* __restrict__ WT,
                                                 const float* __restrict__ bias,
                                                 void* __restrict__ Cout,
                                                 int M, int N, int K) {
    constexpr int WN = 4 / WM;
    constexpr int AM = BM / (WM * 16);
    constexpr int AN = BN / (WN * 16);
    constexpr int AIT = BM / 64;
    constexpr int BIT = BN / 64;

    __shared__ u16 As[2][BM * 32];
    __shared__ u16 Bs[2][BN * 32];

    const int tid  = threadIdx.x;
    const int wave = tid >> 6;
    const int lane = tid & 63;
    const int quad = lane >> 4;
    const int l15  = lane & 15;
    const int wm = wave % WM;
    const int wn = wave / WM;

    const int tm = blockIdx.y * BM;
    const int tn = blockIdx.x * BN;

    auto issue = [&](int kt, int buf) {
#pragma unroll
        for (int it = 0; it < AIT; it++) {
            int cid = it * 256 + tid;
            async16(A + (size_t)(tm + (cid >> 2)) * K + kt + (cid & 3) * 8,
                    (char*)As[buf] + (it * 256 + wave * 64) * 16);
        }
#pragma unroll
        for (int it = 0; it < BIT; it++) {
            int cid = it * 256 + tid;
            async16(WT + (size_t)(tn + (cid >> 2)) * K + kt + (cid & 3) * 8,
                    (char*)Bs[buf] + (it * 256 + wave * 64) * 16);
        }
    };

    f32x4 acc[AM][AN];
#pragma unroll
    for (int i = 0; i < AM; i++)
#pragma unroll
        for (int j = 0; j < AN; j++) acc[i][j] = (f32x4){0.f, 0.f, 0.f, 0.f};

    const int nk = K >> 5;
    issue(0, 0);

    for (int t = 0; t < nk; t++) {
        __syncthreads();             // implicit vmcnt(0) drain: loads(t) done
        if (t + 1 < nk) issue((t + 1) << 5, (t + 1) & 1);
        const int buf = t & 1;

        bf16x8 af[AM], bfr[AN];
#pragma unroll
        for (int i = 0; i < AM; i++)
            af[i] = *(const bf16x8*)((const char*)As[buf] +
                     ((wm * (AM * 16) + i * 16 + l15) * 4 + quad) * 16);
#pragma unroll
        for (int j = 0; j < AN; j++)
            bfr[j] = *(const bf16x8*)((const char*)Bs[buf] +
                     ((wn * (AN * 16) + j * 16 + l15) * 4 + quad) * 16);
#pragma unroll
        for (int i = 0; i < AM; i++)
#pragma unroll
            for (int j = 0; j < AN; j++)
                acc[i][j] = __builtin_amdgcn_mfma_f32_16x16x32_bf16(af[i], bfr[j],
                                                                    acc[i][j], 0, 0, 0);
    }

#pragma unroll
    for (int i = 0; i < AM; i++) {
#pragma unroll
        for (int j = 0; j < AN; j++) {
            int col = tn + wn * (AN * 16) + j * 16 + l15;
            float bv = BIAS ? bias[col] : 0.0f;
#pragma unroll
            for (int r = 0; r < 4; r++) {
                int row = tm + wm * (AM * 16) + i * 16 + quad * 4 + r;
                float v = acc[i][j][r] + bv;
                if (RELU) v = fmaxf(v, 0.0f);
                if (OUTF32) ((float*)Cout)[(size_t)row * N + col] = v;
                else        ((u16*)Cout)[(size_t)row * N + col] = f2bf(v);
            }
        }
    }
}

// ---------------------------------------------------------------------------
// MFMA flash attention v4: 128-row q-tile, TWO independent 64-row chains per
// wave (2x ILP; K/V LDS fragment reads shared by both chains), 2-way split-K.
//  - S computed TRANSPOSED (A=K, B=Q): softmax state per-lane at q=l15.
//  - o_acc rows are q=quad*4+r => alpha broadcast via shfl before rescale.
//  - P gathered to A-fragment via shfl; packed bf16 cvt for P.
//  - Unnormalized partial O (bf16) + (m,l); combine kernel merges splits.
// ---------------------------------------------------------------------------
__global__ __launch_bounds__(256, 2) void flash_attn_mfma(const u16* __restrict__ QKV,
                                                          const u16* __restrict__ VT,
                                                          u16* __restrict__ OP0,
                                                          u16* __restrict__ OP1,
                                                          float2* __restrict__ ML) {
    const int q0 = blockIdx.x * 128;
    const int h  = blockIdx.y;
    const int bz = blockIdx.z;           // b*2 + split
    const int b  = bz >> 1;
    const int split = bz & 1;
    const int tid  = threadIdx.x;
    const int wave = tid >> 6;
    const int lane = tid & 63;
    const int quad = lane >> 4;
    const int l15  = lane & 15;

    __shared__ u16 Ks[2][64 * 64];   // 2 x 8 KB
    __shared__ u16 Vs[2][128 * 64];  // 2 x 16 KB   (48 KB total)

    auto issueKV = [&](int kt, int buf) {
#pragma unroll
        for (int it = 0; it < 2; it++) {
            int cid = it * 256 + tid;
            int c = cid >> 8, p = cid & 255;
            async16(QKV + (size_t)(b * SLEN + kt + (p >> 2)) * 2048 + 512 + h * 64 +
                        c * 32 + (p & 3) * 8,
                    (char*)Ks[buf] + (it * 256 + wave * 64) * 16);
        }
#pragma unroll
        for (int it = 0; it < 4; it++) {
            int cid = it * 256 + tid;
            int c = cid >> 9, p = cid & 511;
            async16(VT + (size_t)((b * 8 + h) * 128 + (p >> 2)) * 2048 + kt +
                        c * 32 + (p & 3) * 8,
                    (char*)Vs[buf] + (it * 256 + wave * 64) * 16);
        }
    };

    bf16x8 qf[2][2];
#pragma unroll
    for (int cn = 0; cn < 2; cn++) {
        const u16* p = QKV + (size_t)(b * SLEN + q0 + cn * 64 + wave * 16 + l15) * 2048 +
                       h * 64 + quad * 8;
        qf[cn][0] = *(const bf16x8*)p;
        qf[cn][1] = *(const bf16x8*)(p + 32);
    }

    f32x4 o_acc[2][8];
#pragma unroll
    for (int cn = 0; cn < 2; cn++)
#pragma unroll
        for (int t = 0; t < 8; t++) o_acc[cn][t] = (f32x4){0.f, 0.f, 0.f, 0.f};
    float m[2] = {-1e30f, -1e30f};
    float l[2] = {0.f, 0.f};

    const int kb0 = split * 1024;
    issueKV(kb0, 0);

    for (int ti = 0; ti < 16; ti++) {
        __syncthreads();                 // implicit vmcnt(0): tiles(ti) landed
        if (ti + 1 < 16) issueKV(kb0 + (ti + 1) * 64, (ti + 1) & 1);
        const int buf = ti & 1;

        // S^T for both chains; K fragments read once, shared
        f32x4 st[2][4];
#pragma unroll
        for (int cn = 0; cn < 2; cn++)
#pragma unroll
            for (int t = 0; t < 4; t++) st[cn][t] = (f32x4){0.f, 0.f, 0.f, 0.f};
#pragma unroll
        for (int c = 0; c < 2; c++)
#pragma unroll
            for (int t = 0; t < 4; t++) {
                bf16x8 kb = *(const bf16x8*)((const char*)Ks[buf] + c * 4096 +
                             ((t * 16 + l15) * 4 + quad) * 16);
                st[0][t] = __builtin_amdgcn_mfma_f32_16x16x32_bf16(kb, qf[0][c],
                                                                   st[0][t], 0, 0, 0);
                st[1][t] = __builtin_amdgcn_mfma_f32_16x16x32_bf16(kb, qf[1][c],
                                                                   st[1][t], 0, 0, 0);
            }

        // softmax, both chains stepwise-interleaved (shared waitcnt windows)
        float mx[2], tp[2];
#pragma unroll
        for (int cn = 0; cn < 2; cn++) {
            float v = -1e30f;
#pragma unroll
            for (int t = 0; t < 4; t++)
#pragma unroll
                for (int r = 0; r < 4; r++) v = fmaxf(v, st[cn][t][r]);
            mx[cn] = v;
        }
        tp[0] = __shfl_xor(mx[0], 16, 64); tp[1] = __shfl_xor(mx[1], 16, 64);
        mx[0] = fmaxf(mx[0], tp[0]);       mx[1] = fmaxf(mx[1], tp[1]);
        tp[0] = __shfl_xor(mx[0], 32, 64); tp[1] = __shfl_xor(mx[1], 32, 64);
        mx[0] = fmaxf(mx[0], tp[0]);       mx[1] = fmaxf(mx[1], tp[1]);

        float alpha[2], ls[2];
        u32 pp[2][4][2];
#pragma unroll
        for (int cn = 0; cn < 2; cn++) {
            float mnew = fmaxf(m[cn], mx[cn]);
            alpha[cn] = exp2f(m[cn] - mnew);
            float s = 0.f;
#pragma unroll
            for (int t = 0; t < 4; t++)
#pragma unroll
                for (int pr = 0; pr < 2; pr++) {
                    float p0 = exp2f(st[cn][t][2 * pr] - mnew);
                    float p1 = exp2f(st[cn][t][2 * pr + 1] - mnew);
                    s += p0 + p1;
                    pp[cn][t][pr] = pk2bf(p0, p1);
                }
            ls[cn] = s;
            m[cn] = mnew;
        }
        tp[0] = __shfl_xor(ls[0], 16, 64); tp[1] = __shfl_xor(ls[1], 16, 64);
        ls[0] += tp[0];                    ls[1] += tp[1];
        tp[0] = __shfl_xor(ls[0], 32, 64); tp[1] = __shfl_xor(ls[1], 32, 64);
        ls[0] += tp[0];                    ls[1] += tp[1];
        l[0] = l[0] * alpha[0] + ls[0];
        l[1] = l[1] * alpha[1] + ls[1];

        // broadcast alpha to accumulator layout (o_acc rows are q=quad*4+r)
        float a4[2][4];
#pragma unroll
        for (int r = 0; r < 4; r++) {
            a4[0][r] = __shfl(alpha[0], quad * 16 + quad * 4 + r, 64);
            a4[1][r] = __shfl(alpha[1], quad * 16 + quad * 4 + r, 64);
        }
#pragma unroll
        for (int cn = 0; cn < 2; cn++)
#pragma unroll
            for (int t = 0; t < 8; t++)
#pragma unroll
                for (int r = 0; r < 4; r++) o_acc[cn][t][r] *= a4[cn][r];

        // PV: gather P A-fragments via shfl (both chains), V fragments shared
#pragma unroll
        for (int c = 0; c < 2; c++) {
            union { u32 u[4]; bf16x8 v; } pu[2];
#pragma unroll
            for (int j2 = 0; j2 < 4; j2++) {
                int src = (2 * (quad & 1) + (j2 >> 1)) * 16 + l15;
                u32 g0a = (u32)__shfl((int)pp[0][2 * c][j2 & 1], src, 64);
                u32 g1a = (u32)__shfl((int)pp[0][2 * c + 1][j2 & 1], src, 64);
                u32 g0b = (u32)__shfl((int)pp[1][2 * c][j2 & 1], src, 64);
                u32 g1b = (u32)__shfl((int)pp[1][2 * c + 1][j2 & 1], src, 64);
                pu[0].u[j2] = (quad & 2) ? g1a : g0a;
                pu[1].u[j2] = (quad & 2) ? g1b : g0b;
            }
#pragma unroll
            for (int t = 0; t < 8; t++) {
                bf16x8 vb = *(const bf16x8*)((const char*)Vs[buf] + c * 8192 +
                             ((t * 16 + l15) * 4 + quad) * 16);
                o_acc[0][t] = __builtin_amdgcn_mfma_f32_16x16x32_bf16(pu[0].v, vb,
                                                                      o_acc[0][t], 0, 0, 0);
                o_acc[1][t] = __builtin_amdgcn_mfma_f32_16x16x32_bf16(pu[1].v, vb,
                                                                      o_acc[1][t], 0, 0, 0);
            }
        }
    }

    // epilogue: unnormalized partial O + (m,l), both chains
    u16* OP = split ? OP1 : OP0;
#pragma unroll
    for (int cn = 0; cn < 2; cn++) {
        if (quad == 0)
            ML[((size_t)(split * 2 + b) * 8 + h) * 2048 + q0 + cn * 64 + wave * 16 + l15] =
                make_float2(m[cn], l[cn]);
#pragma unroll
        for (int r = 0; r < 4; r++) {
            size_t base = ((size_t)(b * SLEN + q0 + cn * 64 + wave * 16 + quad * 4 + r)) * 1024 +
                          h * 128;
#pragma unroll
            for (int t = 0; t < 8; t++)
                OP[base + t * 16 + l15] = f2bf(o_acc[cn][t][r]);
        }
    }
}

// ---------------------------------------------------------------------------
// Merge the two split-K partials: out = SCALING * (O0*w0 + O1*w1) / L
// ---------------------------------------------------------------------------
__global__ __launch_bounds__(256) void attn_combine(const u16* __restrict__ P0,
                                                    const u16* __restrict__ P1,
                                                    const float2* __restrict__ ML,
                                                    u16* __restrict__ AT) {
    int idx = blockIdx.x * 256 + threadIdx.x;   // 4096*1024
    int hv = idx & 1023;
    int row = idx >> 10;                        // b*2048 + q
    int h = hv >> 7;
    int b = row >> 11, q = row & 2047;
    float2 ml0 = ML[((size_t)(0 + b) * 8 + h) * 2048 + q];
    float2 ml1 = ML[((size_t)(2 + b) * 8 + h) * 2048 + q];
    float M = fmaxf(ml0.x, ml1.x);
    float w0 = exp2f(ml0.x - M), w1 = exp2f(ml1.x - M);
    float L = ml0.y * w0 + ml1.y * w1;
    float o = bf2f(P0[idx]) * w0 + bf2f(P1[idx]) * w1;
    AT[idx] = f2bf(ATT_SCALING * o / L);
}

// ---------------------------------------------------------------------------
// LN(X + R) * g + be : fp32 in, fp32 + bf16 out (one block per 512-row)
// ---------------------------------------------------------------------------
__global__ __launch_bounds__(256) void addln_kernel(const float* __restrict__ X,
                                                    const float* __restrict__ R,
                                                    const float* __restrict__ g,
                                                    const float* __restrict__ be,
                                                    float* __restrict__ dstf,
                                                    u16* __restrict__ dstb) {
    const int row = blockIdx.x;
    const int tid = threadIdx.x;
    __shared__ float red[256];
    size_t off = (size_t)row * HIDDEN;
    float v0 = X[off + tid] + R[off + tid];
    float v1 = X[off + tid + 256] + R[off + tid + 256];
    red[tid] = v0 + v1;
    __syncthreads();
    for (int s = 128; s > 0; s >>= 1) { if (tid < s) red[tid] += red[tid + s]; __syncthreads(); }
    float mu = red[0] * (1.0f / HIDDEN);
    __syncthreads();
    float d0 = v0 - mu, d1 = v1 - mu;
    red[tid] = d0 * d0 + d1 * d1;
    __syncthreads();
    for (int s = 128; s > 0; s >>= 1) { if (tid < s) red[tid] += red[tid + s]; __syncthreads(); }
    float rstd = rsqrtf(red[0] * (1.0f / HIDDEN) + LN_EPS);
    float o0 = d0 * rstd * g[tid] + be[tid];
    float o1 = d1 * rstd * g[tid + 256] + be[tid + 256];
    dstf[off + tid] = o0;
    dstf[off + tid + 256] = o1;
    dstb[off + tid] = f2bf(o0);
    dstb[off + tid + 256] = f2bf(o1);
}

// ---------------------------------------------------------------------------
extern "C" void kernel_launch(void* const* d_in, const int* in_sizes, int n_in,
                              void* d_out, int out_size, void* d_ws, size_t ws_size,
                              hipStream_t stream) {
    const float* x   = (const float*)d_in[0];
    const float* Wq  = (const float*)d_in[1];
    const float* Wk  = (const float*)d_in[2];
    const float* Wv  = (const float*)d_in[3];
    const float* Wo  = (const float*)d_in[4];
    const float* W1  = (const float*)d_in[5];
    const float* b1  = (const float*)d_in[6];
    const float* W2  = (const float*)d_in[7];
    const float* b2  = (const float*)d_in[8];
    const float* g1  = (const float*)d_in[9];
    const float* be1 = (const float*)d_in[10];
    const float* g2  = (const float*)d_in[11];
    const float* be2 = (const float*)d_in[12];
    float* out = (float*)d_out;

    // Workspace (63 MB used):
    //  R1 [ 0..8M)  : A_f32 residual -> F2 fp32
    //  R2 [ 8..16M) : VT (attn)      -> Y_f32
    //  R3 [16..24M) : A_bf (4M)      -> O-partial split1 (8M) -> P fp32 (8M)
    //  R4 [24..40M) : QKV bf16 (16M) -> F1 bf16
    //  R5 [40..48M) : O-partial split0 / AT bf16 (8M) -> Y_bf (4M)
    //  R6 [48..62M) : bf16 transposed weights
    //  R7 [62..62.5M): xpos table ; [62.5..63M): attention (m,l)
    const size_t MB = 1u << 20;
    char* w = (char*)d_ws;
    float*  R1f  = (float*)(w);
    u16*    VTg  = (u16*)(w + 8 * MB);
    float*  Yf   = (float*)(w + 8 * MB);
    u16*    A_bf = (u16*)(w + 16 * MB);
    u16*    OP1  = (u16*)(w + 16 * MB);
    float*  Pf   = (float*)(w + 16 * MB);
    u16*    QKV  = (u16*)(w + 24 * MB);
    u16*    F1   = (u16*)(w + 24 * MB);
    u16*    OP0  = (u16*)(w + 40 * MB);
    u16*    AT   = (u16*)(w + 40 * MB);
    u16*    Y_bf = (u16*)(w + 40 * MB);
    float2* xtab = (float2*)(w + 62 * MB);
    float2* ML   = (float2*)(w + 62 * MB + 512 * 1024);

    cvt_x<<<MROWS * HIDDEN / 256, 256, 0, stream>>>(x, R1f, A_bf);
    xpos_table<<<256, 256, 0, stream>>>(xtab);

    for (int l = 0; l < LAYERS; l++) {
        u16* WqkvT = (u16*)(w + 48 * MB + (size_t)l * 2 * MB);
        u16* WoT   = (u16*)(w + 52 * MB + (size_t)l * 1 * MB);
        u16* W1T   = (u16*)(w + 54 * MB + (size_t)l * 2 * MB);
        u16* W2T   = (u16*)(w + 58 * MB + (size_t)l * 2 * MB);
        wtrans<<<dim3(16, 16), 256, 0, stream>>>(Wq + (size_t)l * 512 * 512,  WqkvT,              512, 512);
        wtrans<<<dim3(16, 16), 256, 0, stream>>>(Wk + (size_t)l * 512 * 512,  WqkvT + 512 * 512,  512, 512);
        wtrans<<<dim3(32, 16), 256, 0, stream>>>(Wv + (size_t)l * 512 * 1024, WqkvT + 1024 * 512, 512, 1024);
        wtrans<<<dim3(16, 32), 256, 0, stream>>>(Wo + (size_t)l * 1024 * 512, WoT,                1024, 512);
        wtrans<<<dim3(64, 16), 256, 0, stream>>>(W1 + (size_t)l * 512 * 2048, W1T,                512, 2048);
        wtrans<<<dim3(16, 64), 256, 0, stream>>>(W2 + (size_t)l * 2048 * 512, W2T,                2048, 512);
    }

    for (int l = 0; l < LAYERS; l++) {
        u16* WqkvT = (u16*)(w + 48 * MB + (size_t)l * 2 * MB);
        u16* WoT   = (u16*)(w + 52 * MB + (size_t)l * 1 * MB);
        u16* W1T   = (u16*)(w + 54 * MB + (size_t)l * 2 * MB);
        u16* W2T   = (u16*)(w + 58 * MB + (size_t)l * 2 * MB);
        const float* b1_l  = b1 + (size_t)l * FFN_DIM;
        const float* b2_l  = b2 + (size_t)l * HIDDEN;
        const float* g1_l  = g1 + (size_t)l * HIDDEN;
        const float* be1_l = be1 + (size_t)l * HIDDEN;
        const float* g2_l  = g2 + (size_t)l * HIDDEN;
        const float* be2_l = be2 + (size_t)l * HIDDEN;

        // QKV = A_bf @ [Wq|Wk|Wv]  (bf16 out), 512 blocks
        gemm_mfma<128, 128, 2, 0, 0, 0><<<dim3(16, 32), 256, 0, stream>>>(
            A_bf, WqkvT, nullptr, QKV, MROWS, 2048, 512);

        xpos_kernel<<<4096, 256, 0, stream>>>(QKV, xtab);
        vtrans<<<dim3(32, 2, 16), 256, 0, stream>>>(QKV, VTg);

        // flash attention: 128-q tiles, 2-way split-K (z = b*2 + split)
        flash_attn_mfma<<<dim3(16, 8, 4), 256, 0, stream>>>(QKV, VTg, OP0, OP1, ML);
        attn_combine<<<MROWS * 1024 / 256, 256, 0, stream>>>(OP0, OP1, ML, AT);

        // P = AT @ Wo (fp32 out), 64x64 tiles -> 512 blocks
        gemm_mfma<64, 64, 2, 1, 0, 0><<<dim3(8, 64), 256, 0, stream>>>(
            AT, WoT, nullptr, Pf, MROWS, 512, 1024);

        // Y = LN(A + P)
        addln_kernel<<<MROWS, 256, 0, stream>>>(R1f, Pf, g1_l, be1_l, Yf, Y_bf);

        // F1 = relu(Y @ W1 + b1) (bf16 out), 512 blocks
        gemm_mfma<128, 128, 2, 0, 1, 1><<<dim3(16, 32), 256, 0, stream>>>(
            Y_bf, W1T, b1_l, F1, MROWS, 2048, 512);

        // F2 = F1 @ W2 + b2 (fp32 out), 64x64 tiles -> 512 blocks
        gemm_mfma<64, 64, 2, 1, 1, 0><<<dim3(8, 64), 256, 0, stream>>>(
            F1, W2T, b2_l, R1f, MROWS, 512, 2048);

        // x_next = LN(Y + F2)
        float* dstf = (l == LAYERS - 1) ? out : R1f;
        addln_kernel<<<MROWS, 256, 0, stream>>>(Yf, R1f, g2_l, be2_l, dstf, A_bf);
    }
}

// Round 9
// 467.016 us; speedup vs baseline: 1.2660x; 1.0097x over previous
//
#include <hip/hip_runtime.h>
#include <hip/hip_bf16.h>
#include <math.h>

#define LAYERS 2
#define HIDDEN 512
#define FFN_DIM 2048
#define HEADS 8
#define SLEN 2048
#define BSZ 2
#define MROWS 4096
#define ATT_SCALING 0.125f
#define LN_EPS 1e-5f
#define SCALE_BASE 512.0f
#define LOG2E 1.4426950408889634f

typedef unsigned short u16;
typedef unsigned int u32;
typedef __attribute__((ext_vector_type(8))) short bf16x8;   // 8 bf16 = 4 VGPR
typedef __attribute__((ext_vector_type(4))) float f32x4;

__device__ __forceinline__ float bf2f(u16 u) {
    union { u32 i; float f; } v; v.i = ((u32)u) << 16; return v.f;
}
__device__ __forceinline__ u16 f2bf(float f) {
    union { float f; u32 i; } v; v.f = f;
    u32 r = v.i + 0x7FFFu + ((v.i >> 16) & 1u);   // RNE
    return (u16)(r >> 16);
}
__device__ __forceinline__ u32 pk2bf(float a, float b) {   // packed RNE cvt
    union { __hip_bfloat162 h; u32 u; } v;
    v.h = __float22bfloat162_rn(make_float2(a, b));
    return v.u;
}
__device__ __forceinline__ void async16(const void* g, void* l) {
    __builtin_amdgcn_global_load_lds((const __attribute__((address_space(1))) void*)g,
                                     (__attribute__((address_space(3))) void*)l, 16, 0, 0);
}

// ---------------------------------------------------------------------------
// fp32 [K][N] -> bf16 [N][K] transpose (weights prep)
// ---------------------------------------------------------------------------
__global__ __launch_bounds__(256) void wtrans(const float* __restrict__ in,
                                              u16* __restrict__ out,
                                              int K, int N) {
    __shared__ float t[32][33];
    int tx = threadIdx.x & 31, ty = threadIdx.x >> 5;       // 32 x 8
    int k0 = blockIdx.y * 32, n0 = blockIdx.x * 32;
#pragma unroll
    for (int i = 0; i < 4; i++)
        t[ty + 8 * i][tx] = in[(size_t)(k0 + ty + 8 * i) * N + n0 + tx];
    __syncthreads();
#pragma unroll
    for (int i = 0; i < 4; i++)
        out[(size_t)(n0 + ty + 8 * i) * K + k0 + tx] = f2bf(t[tx][ty + 8 * i]);
}

// ---------------------------------------------------------------------------
// x fp32 -> residual fp32 copy + bf16 copy
// ---------------------------------------------------------------------------
__global__ __launch_bounds__(256) void cvt_x(const float* __restrict__ x,
                                             float* __restrict__ Af,
                                             u16* __restrict__ Ab) {
    int i = blockIdx.x * 256 + threadIdx.x;
    float v = x[i];
    Af[i] = v;
    Ab[i] = f2bf(v);
}

// ---------------------------------------------------------------------------
// xPos cos/sin table: tab[s*32+j] = (cos*scale, sin*scale)
// ---------------------------------------------------------------------------
__global__ __launch_bounds__(256) void xpos_table(float2* __restrict__ tab) {
    int idx = blockIdx.x * 256 + threadIdx.x;   // 2048*32 = 65536
    int j = idx & 31;
    int s = idx >> 5;
    float base = (2.0f * j + 0.4f * 64.0f) / (1.4f * 64.0f);
    float pos = (float)(s - 1024);
    float scale = powf(base, pos / SCALE_BASE);
    float inv_freq = powf(10000.0f, -(float)j / 32.0f);
    float ang = (float)s * inv_freq;
    tab[idx] = make_float2(cosf(ang) * scale, sinf(ang) * scale);
}

// ---------------------------------------------------------------------------
// xPos applied in-place to Q (cols h*64+..) and K (cols 512+h*64+..) of QKV
// bf16, packed u32 accesses. Q additionally scaled by LOG2E (exp2 softmax).
// ---------------------------------------------------------------------------
__global__ __launch_bounds__(256) void xpos_kernel(u16* __restrict__ QKV,
                                                   const float2* __restrict__ tab) {
    int idx = blockIdx.x * 256 + threadIdx.x;   // 2^20
    int j = idx & 31;
    int h = (idx >> 5) & 7;
    int s = (idx >> 8) & 2047;
    int b = idx >> 19;

    float2 cssn = tab[s * 32 + j];
    float cs = cssn.x, sn = cssn.y;

    size_t off = (size_t)(b * SLEN + s) * 2048 + h * 64 + 2 * j;
    u32* pq = (u32*)(QKV + off);
    u32* pk = (u32*)(QKV + off + 512);

    u32 qv = *pq;
    float q0 = bf2f((u16)(qv & 0xffff)), q1 = bf2f((u16)(qv >> 16));
    *pq = pk2bf((q0 * cs - q1 * sn) * LOG2E, (q1 * cs + q0 * sn) * LOG2E);

    u32 kv = *pk;
    float k0 = bf2f((u16)(kv & 0xffff)), k1 = bf2f((u16)(kv >> 16));
    *pk = pk2bf(k0 * cs - k1 * sn, k1 * cs + k0 * sn);
}

// ---------------------------------------------------------------------------
// V section of QKV -> VT[(b*8+h)*128 + v][s]  (bf16 -> bf16 transpose)
// ---------------------------------------------------------------------------
__global__ __launch_bounds__(256) void vtrans(const u16* __restrict__ QKV,
                                              u16* __restrict__ VT) {
    __shared__ u16 t[64][65];
    int b = blockIdx.z >> 3, h = blockIdx.z & 7;
    int s0 = blockIdx.x * 64, v0 = blockIdx.y * 64;
    int tid = threadIdx.x;
#pragma unroll
    for (int i = 0; i < 16; i++) {
        int e = tid + i * 256; int r = e >> 6, c = e & 63;      // r: s, c: v
        t[r][c] = QKV[(size_t)(b * SLEN + s0 + r) * 2048 + 1024 + h * 128 + v0 + c];
    }
    __syncthreads();
#pragma unroll
    for (int i = 0; i < 16; i++) {
        int e = tid + i * 256; int r = e >> 6, c = e & 63;      // r: v, c: s
        VT[(size_t)((b * 8 + h) * 128 + v0 + r) * 2048 + s0 + c] = t[c][r];
    }
}

// ---------------------------------------------------------------------------
// MFMA GEMM, software-pipelined (unchanged from round 4).
// ---------------------------------------------------------------------------
template <int BM, int BN, int WM, int OUTF32, int BIAS, int RELU>
__global__ __launch_bounds__(256) void gemm_mfma(const u16* __restrict__ A,
                                                 const u16* __restrict__ WT,
                                                 const float* __restrict__ bias,
                                                 void* __restrict__ Cout,
                                                 int M, int N, int K) {
    constexpr int WN = 4 / WM;
    constexpr int AM = BM / (WM * 16);
    constexpr int AN = BN / (WN * 16);
    constexpr int AIT = BM / 64;
    constexpr int BIT = BN / 64;

    __shared__ u16 As[2][BM * 32];
    __shared__ u16 Bs[2][BN * 32];

    const int tid  = threadIdx.x;
    const int wave = tid >> 6;
    const int lane = tid & 63;
    const int quad = lane >> 4;
    const int l15  = lane & 15;
    const int wm = wave % WM;
    const int wn = wave / WM;

    const int tm = blockIdx.y * BM;
    const int tn = blockIdx.x * BN;

    auto issue = [&](int kt, int buf) {
#pragma unroll
        for (int it = 0; it < AIT; it++) {
            int cid = it * 256 + tid;
            async16(A + (size_t)(tm + (cid >> 2)) * K + kt + (cid & 3) * 8,
                    (char*)As[buf] + (it * 256 + wave * 64) * 16);
        }
#pragma unroll
        for (int it = 0; it < BIT; it++) {
            int cid = it * 256 + tid;
            async16(WT + (size_t)(tn + (cid >> 2)) * K + kt + (cid & 3) * 8,
                    (char*)Bs[buf] + (it * 256 + wave * 64) * 16);
        }
    };

    f32x4 acc[AM][AN];
#pragma unroll
    for (int i = 0; i < AM; i++)
#pragma unroll
        for (int j = 0; j < AN; j++) acc[i][j] = (f32x4){0.f, 0.f, 0.f, 0.f};

    const int nk = K >> 5;
    issue(0, 0);

    for (int t = 0; t < nk; t++) {
        __syncthreads();             // implicit vmcnt(0) drain: loads(t) done
        if (t + 1 < nk) issue((t + 1) << 5, (t + 1) & 1);
        const int buf = t & 1;

        bf16x8 af[AM], bfr[AN];
#pragma unroll
        for (int i = 0; i < AM; i++)
            af[i] = *(const bf16x8*)((const char*)As[buf] +
                     ((wm * (AM * 16) + i * 16 + l15) * 4 + quad) * 16);
#pragma unroll
        for (int j = 0; j < AN; j++)
            bfr[j] = *(const bf16x8*)((const char*)Bs[buf] +
                     ((wn * (AN * 16) + j * 16 + l15) * 4 + quad) * 16);
#pragma unroll
        for (int i = 0; i < AM; i++)
#pragma unroll
            for (int j = 0; j < AN; j++)
                acc[i][j] = __builtin_amdgcn_mfma_f32_16x16x32_bf16(af[i], bfr[j],
                                                                    acc[i][j], 0, 0, 0);
    }

#pragma unroll
    for (int i = 0; i < AM; i++) {
#pragma unroll
        for (int j = 0; j < AN; j++) {
            int col = tn + wn * (AN * 16) + j * 16 + l15;
            float bv = BIAS ? bias[col] : 0.0f;
#pragma unroll
            for (int r = 0; r < 4; r++) {
                int row = tm + wm * (AM * 16) + i * 16 + quad * 4 + r;
                float v = acc[i][j][r] + bv;
                if (RELU) v = fmaxf(v, 0.0f);
                if (OUTF32) ((float*)Cout)[(size_t)row * N + col] = v;
                else        ((u16*)Cout)[(size_t)row * N + col] = f2bf(v);
            }
        }
    }
}

// ---------------------------------------------------------------------------
// MFMA flash attention v5: 128-q tile, 2 chains/wave, 2-way split-K.
//  - XCD swizzle: grid = (h, qtile, b*2+split) so id%8 = h -> all blocks
//    sharing one head's K/VT land on one XCD's L2.
//  - S^T = mfma(K, Q): softmax state per-lane at q=l15.
//  - PV TRANSPOSED: mfma(V^T, P^T) -> o_acc = O^T[v][q=l15]; alpha rescale is
//    a plain per-lane multiply (no broadcast shfls).
//  - Epilogue: packed u32 scattered stores (16B row segments, no waste).
// ---------------------------------------------------------------------------
__global__ __launch_bounds__(256, 2) void flash_attn_mfma(const u16* __restrict__ QKV,
                                                          const u16* __restrict__ VT,
                                                          u16* __restrict__ OP0,
                                                          u16* __restrict__ OP1,
                                                          float2* __restrict__ ML) {
    const int h  = blockIdx.x;           // XCD swizzle: x = head
    const int q0 = blockIdx.y * 128;
    const int bz = blockIdx.z;           // b*2 + split
    const int b  = bz >> 1;
    const int split = bz & 1;
    const int tid  = threadIdx.x;
    const int wave = tid >> 6;
    const int lane = tid & 63;
    const int quad = lane >> 4;
    const int l15  = lane & 15;

    __shared__ u16 Ks[2][64 * 64];   // 2 x 8 KB
    __shared__ u16 Vs[2][128 * 64];  // 2 x 16 KB   (48 KB total)

    auto issueKV = [&](int kt, int buf) {
#pragma unroll
        for (int it = 0; it < 2; it++) {
            int cid = it * 256 + tid;
            int c = cid >> 8, p = cid & 255;
            async16(QKV + (size_t)(b * SLEN + kt + (p >> 2)) * 2048 + 512 + h * 64 +
                        c * 32 + (p & 3) * 8,
                    (char*)Ks[buf] + (it * 256 + wave * 64) * 16);
        }
#pragma unroll
        for (int it = 0; it < 4; it++) {
            int cid = it * 256 + tid;
            int c = cid >> 9, p = cid & 511;
            async16(VT + (size_t)((b * 8 + h) * 128 + (p >> 2)) * 2048 + kt +
                        c * 32 + (p & 3) * 8,
                    (char*)Vs[buf] + (it * 256 + wave * 64) * 16);
        }
    };

    bf16x8 qf[2][2];
#pragma unroll
    for (int cn = 0; cn < 2; cn++) {
        const u16* p = QKV + (size_t)(b * SLEN + q0 + cn * 64 + wave * 16 + l15) * 2048 +
                       h * 64 + quad * 8;
        qf[cn][0] = *(const bf16x8*)p;
        qf[cn][1] = *(const bf16x8*)(p + 32);
    }

    f32x4 o_acc[2][8];
#pragma unroll
    for (int cn = 0; cn < 2; cn++)
#pragma unroll
        for (int t = 0; t < 8; t++) o_acc[cn][t] = (f32x4){0.f, 0.f, 0.f, 0.f};
    float m[2] = {-1e30f, -1e30f};
    float l[2] = {0.f, 0.f};

    const int kb0 = split * 1024;
    issueKV(kb0, 0);

    for (int ti = 0; ti < 16; ti++) {
        __syncthreads();                 // implicit vmcnt(0): tiles(ti) landed
        if (ti + 1 < 16) issueKV(kb0 + (ti + 1) * 64, (ti + 1) & 1);
        const int buf = ti & 1;

        // S^T for both chains; K fragments read once, shared
        f32x4 st[2][4];
#pragma unroll
        for (int cn = 0; cn < 2; cn++)
#pragma unroll
            for (int t = 0; t < 4; t++) st[cn][t] = (f32x4){0.f, 0.f, 0.f, 0.f};
#pragma unroll
        for (int c = 0; c < 2; c++)
#pragma unroll
            for (int t = 0; t < 4; t++) {
                bf16x8 kb = *(const bf16x8*)((const char*)Ks[buf] + c * 4096 +
                             ((t * 16 + l15) * 4 + quad) * 16);
                st[0][t] = __builtin_amdgcn_mfma_f32_16x16x32_bf16(kb, qf[0][c],
                                                                   st[0][t], 0, 0, 0);
                st[1][t] = __builtin_amdgcn_mfma_f32_16x16x32_bf16(kb, qf[1][c],
                                                                   st[1][t], 0, 0, 0);
            }

        // softmax, both chains stepwise-interleaved (shared waitcnt windows)
        float mx[2], tp[2];
#pragma unroll
        for (int cn = 0; cn < 2; cn++) {
            float v = -1e30f;
#pragma unroll
            for (int t = 0; t < 4; t++)
#pragma unroll
                for (int r = 0; r < 4; r++) v = fmaxf(v, st[cn][t][r]);
            mx[cn] = v;
        }
        tp[0] = __shfl_xor(mx[0], 16, 64); tp[1] = __shfl_xor(mx[1], 16, 64);
        mx[0] = fmaxf(mx[0], tp[0]);       mx[1] = fmaxf(mx[1], tp[1]);
        tp[0] = __shfl_xor(mx[0], 32, 64); tp[1] = __shfl_xor(mx[1], 32, 64);
        mx[0] = fmaxf(mx[0], tp[0]);       mx[1] = fmaxf(mx[1], tp[1]);

        float alpha[2], ls[2];
        u32 pp[2][4][2];
#pragma unroll
        for (int cn = 0; cn < 2; cn++) {
            float mnew = fmaxf(m[cn], mx[cn]);
            alpha[cn] = exp2f(m[cn] - mnew);
            float s = 0.f;
#pragma unroll
            for (int t = 0; t < 4; t++)
#pragma unroll
                for (int pr = 0; pr < 2; pr++) {
                    float p0 = exp2f(st[cn][t][2 * pr] - mnew);
                    float p1 = exp2f(st[cn][t][2 * pr + 1] - mnew);
                    s += p0 + p1;
                    pp[cn][t][pr] = pk2bf(p0, p1);
                }
            ls[cn] = s;
            m[cn] = mnew;
        }
        tp[0] = __shfl_xor(ls[0], 16, 64); tp[1] = __shfl_xor(ls[1], 16, 64);
        ls[0] += tp[0];                    ls[1] += tp[1];
        tp[0] = __shfl_xor(ls[0], 32, 64); tp[1] = __shfl_xor(ls[1], 32, 64);
        ls[0] += tp[0];                    ls[1] += tp[1];
        l[0] = l[0] * alpha[0] + ls[0];
        l[1] = l[1] * alpha[1] + ls[1];

        // rescale: o_acc is O^T[v][q=l15]; alpha lives at q=l15 -> plain mul
#pragma unroll
        for (int cn = 0; cn < 2; cn++)
#pragma unroll
            for (int t = 0; t < 8; t++)
#pragma unroll
                for (int r = 0; r < 4; r++) o_acc[cn][t][r] *= alpha[cn];

        // PV (transposed): gather P^T B-fragments via shfl, A = V^T from LDS
#pragma unroll
        for (int c = 0; c < 2; c++) {
            union { u32 u[4]; bf16x8 v; } pu[2];
#pragma unroll
            for (int j2 = 0; j2 < 4; j2++) {
                int src = (2 * (quad & 1) + (j2 >> 1)) * 16 + l15;
                u32 g0a = (u32)__shfl((int)pp[0][2 * c][j2 & 1], src, 64);
                u32 g1a = (u32)__shfl((int)pp[0][2 * c + 1][j2 & 1], src, 64);
                u32 g0b = (u32)__shfl((int)pp[1][2 * c][j2 & 1], src, 64);
                u32 g1b = (u32)__shfl((int)pp[1][2 * c + 1][j2 & 1], src, 64);
                pu[0].u[j2] = (quad & 2) ? g1a : g0a;
                pu[1].u[j2] = (quad & 2) ? g1b : g0b;
            }
#pragma unroll
            for (int t = 0; t < 8; t++) {
                bf16x8 vb = *(const bf16x8*)((const char*)Vs[buf] + c * 8192 +
                             ((t * 16 + l15) * 4 + quad) * 16);
                o_acc[0][t] = __builtin_amdgcn_mfma_f32_16x16x32_bf16(vb, pu[0].v,
                                                                      o_acc[0][t], 0, 0, 0);
                o_acc[1][t] = __builtin_amdgcn_mfma_f32_16x16x32_bf16(vb, pu[1].v,
                                                                      o_acc[1][t], 0, 0, 0);
            }
        }
    }

    // epilogue: o_acc[cn][t][r] = O^T[v = t*16+quad*4+r][q = l15], packed u32
    u16* OP = split ? OP1 : OP0;
#pragma unroll
    for (int cn = 0; cn < 2; cn++) {
        if (quad == 0)
            ML[((size_t)(split * 2 + b) * 8 + h) * 2048 + q0 + cn * 64 + wave * 16 + l15] =
                make_float2(m[cn], l[cn]);
        size_t rowbase = ((size_t)(b * SLEN + q0 + cn * 64 + wave * 16 + l15)) * 1024 +
                         h * 128;
#pragma unroll
        for (int t = 0; t < 8; t++)
#pragma unroll
            for (int rp = 0; rp < 2; rp++)
                *(u32*)(OP + rowbase + t * 16 + quad * 4 + 2 * rp) =
                    pk2bf(o_acc[cn][t][2 * rp], o_acc[cn][t][2 * rp + 1]);
    }
}

// ---------------------------------------------------------------------------
// Merge the two split-K partials: out = SCALING * (O0*w0 + O1*w1) / L
// ---------------------------------------------------------------------------
__global__ __launch_bounds__(256) void attn_combine(const u16* __restrict__ P0,
                                                    const u16* __restrict__ P1,
                                                    const float2* __restrict__ ML,
                                                    u16* __restrict__ AT) {
    int idx = blockIdx.x * 256 + threadIdx.x;   // 4096*1024
    int hv = idx & 1023;
    int row = idx >> 10;                        // b*2048 + q
    int h = hv >> 7;
    int b = row >> 11, q = row & 2047;
    float2 ml0 = ML[((size_t)(0 + b) * 8 + h) * 2048 + q];
    float2 ml1 = ML[((size_t)(2 + b) * 8 + h) * 2048 + q];
    float M = fmaxf(ml0.x, ml1.x);
    float w0 = exp2f(ml0.x - M), w1 = exp2f(ml1.x - M);
    float L = ml0.y * w0 + ml1.y * w1;
    float o = bf2f(P0[idx]) * w0 + bf2f(P1[idx]) * w1;
    AT[idx] = f2bf(ATT_SCALING * o / L);
}

// ---------------------------------------------------------------------------
// LN(X + R) * g + be : fp32 in, fp32 + bf16 out (one block per 512-row)
// ---------------------------------------------------------------------------
__global__ __launch_bounds__(256) void addln_kernel(const float* __restrict__ X,
                                                    const float* __restrict__ R,
                                                    const float* __restrict__ g,
                                                    const float* __restrict__ be,
                                                    float* __restrict__ dstf,
                                                    u16* __restrict__ dstb) {
    const int row = blockIdx.x;
    const int tid = threadIdx.x;
    __shared__ float red[256];
    size_t off = (size_t)row * HIDDEN;
    float v0 = X[off + tid] + R[off + tid];
    float v1 = X[off + tid + 256] + R[off + tid + 256];
    red[tid] = v0 + v1;
    __syncthreads();
    for (int s = 128; s > 0; s >>= 1) { if (tid < s) red[tid] += red[tid + s]; __syncthreads(); }
    float mu = red[0] * (1.0f / HIDDEN);
    __syncthreads();
    float d0 = v0 - mu, d1 = v1 - mu;
    red[tid] = d0 * d0 + d1 * d1;
    __syncthreads();
    for (int s = 128; s > 0; s >>= 1) { if (tid < s) red[tid] += red[tid + s]; __syncthreads(); }
    float rstd = rsqrtf(red[0] * (1.0f / HIDDEN) + LN_EPS);
    float o0 = d0 * rstd * g[tid] + be[tid];
    float o1 = d1 * rstd * g[tid + 256] + be[tid + 256];
    dstf[off + tid] = o0;
    dstf[off + tid + 256] = o1;
    dstb[off + tid] = f2bf(o0);
    dstb[off + tid + 256] = f2bf(o1);
}

// ---------------------------------------------------------------------------
extern "C" void kernel_launch(void* const* d_in, const int* in_sizes, int n_in,
                              void* d_out, int out_size, void* d_ws, size_t ws_size,
                              hipStream_t stream) {
    const float* x   = (const float*)d_in[0];
    const float* Wq  = (const float*)d_in[1];
    const float* Wk  = (const float*)d_in[2];
    const float* Wv  = (const float*)d_in[3];
    const float* Wo  = (const float*)d_in[4];
    const float* W1  = (const float*)d_in[5];
    const float* b1  = (const float*)d_in[6];
    const float* W2  = (const float*)d_in[7];
    const float* b2  = (const float*)d_in[8];
    const float* g1  = (const float*)d_in[9];
    const float* be1 = (const float*)d_in[10];
    const float* g2  = (const float*)d_in[11];
    const float* be2 = (const float*)d_in[12];
    float* out = (float*)d_out;

    // Workspace (63 MB used):
    //  R1 [ 0..8M)  : A_f32 residual -> F2 fp32
    //  R2 [ 8..16M) : VT (attn)      -> Y_f32
    //  R3 [16..24M) : A_bf (4M)      -> O-partial split1 (8M) -> P fp32 (8M)
    //  R4 [24..40M) : QKV bf16 (16M) -> F1 bf16
    //  R5 [40..48M) : O-partial split0 / AT bf16 (8M) -> Y_bf (4M)
    //  R6 [48..62M) : bf16 transposed weights
    //  R7 [62..62.5M): xpos table ; [62.5..63M): attention (m,l)
    const size_t MB = 1u << 20;
    char* w = (char*)d_ws;
    float*  R1f  = (float*)(w);
    u16*    VTg  = (u16*)(w + 8 * MB);
    float*  Yf   = (float*)(w + 8 * MB);
    u16*    A_bf = (u16*)(w + 16 * MB);
    u16*    OP1  = (u16*)(w + 16 * MB);
    float*  Pf   = (float*)(w + 16 * MB);
    u16*    QKV  = (u16*)(w + 24 * MB);
    u16*    F1   = (u16*)(w + 24 * MB);
    u16*    OP0  = (u16*)(w + 40 * MB);
    u16*    AT   = (u16*)(w + 40 * MB);
    u16*    Y_bf = (u16*)(w + 40 * MB);
    float2* xtab = (float2*)(w + 62 * MB);
    float2* ML   = (float2*)(w + 62 * MB + 512 * 1024);

    cvt_x<<<MROWS * HIDDEN / 256, 256, 0, stream>>>(x, R1f, A_bf);
    xpos_table<<<256, 256, 0, stream>>>(xtab);

    for (int l = 0; l < LAYERS; l++) {
        u16* WqkvT = (u16*)(w + 48 * MB + (size_t)l * 2 * MB);
        u16* WoT   = (u16*)(w + 52 * MB + (size_t)l * 1 * MB);
        u16* W1T   = (u16*)(w + 54 * MB + (size_t)l * 2 * MB);
        u16* W2T   = (u16*)(w + 58 * MB + (size_t)l * 2 * MB);
        wtrans<<<dim3(16, 16), 256, 0, stream>>>(Wq + (size_t)l * 512 * 512,  WqkvT,              512, 512);
        wtrans<<<dim3(16, 16), 256, 0, stream>>>(Wk + (size_t)l * 512 * 512,  WqkvT + 512 * 512,  512, 512);
        wtrans<<<dim3(32, 16), 256, 0, stream>>>(Wv + (size_t)l * 512 * 1024, WqkvT + 1024 * 512, 512, 1024);
        wtrans<<<dim3(16, 32), 256, 0, stream>>>(Wo + (size_t)l * 1024 * 512, WoT,                1024, 512);
        wtrans<<<dim3(64, 16), 256, 0, stream>>>(W1 + (size_t)l * 512 * 2048, W1T,                512, 2048);
        wtrans<<<dim3(16, 64), 256, 0, stream>>>(W2 + (size_t)l * 2048 * 512, W2T,                2048, 512);
    }

    for (int l = 0; l < LAYERS; l++) {
        u16* WqkvT = (u16*)(w + 48 * MB + (size_t)l * 2 * MB);
        u16* WoT   = (u16*)(w + 52 * MB + (size_t)l * 1 * MB);
        u16* W1T   = (u16*)(w + 54 * MB + (size_t)l * 2 * MB);
        u16* W2T   = (u16*)(w + 58 * MB + (size_t)l * 2 * MB);
        const float* b1_l  = b1 + (size_t)l * FFN_DIM;
        const float* b2_l  = b2 + (size_t)l * HIDDEN;
        const float* g1_l  = g1 + (size_t)l * HIDDEN;
        const float* be1_l = be1 + (size_t)l * HIDDEN;
        const float* g2_l  = g2 + (size_t)l * HIDDEN;
        const float* be2_l = be2 + (size_t)l * HIDDEN;

        // QKV = A_bf @ [Wq|Wk|Wv]  (bf16 out), 512 blocks
        gemm_mfma<128, 128, 2, 0, 0, 0><<<dim3(16, 32), 256, 0, stream>>>(
            A_bf, WqkvT, nullptr, QKV, MROWS, 2048, 512);

        xpos_kernel<<<4096, 256, 0, stream>>>(QKV, xtab);
        vtrans<<<dim3(32, 2, 16), 256, 0, stream>>>(QKV, VTg);

        // flash attention: XCD-swizzled grid (h, qtile, b*2+split)
        flash_attn_mfma<<<dim3(8, 16, 4), 256, 0, stream>>>(QKV, VTg, OP0, OP1, ML);
        attn_combine<<<MROWS * 1024 / 256, 256, 0, stream>>>(OP0, OP1, ML, AT);

        // P = AT @ Wo (fp32 out), 64x64 tiles -> 512 blocks
        gemm_mfma<64, 64, 2, 1, 0, 0><<<dim3(8, 64), 256, 0, stream>>>(
            AT, WoT, nullptr, Pf, MROWS, 512, 1024);

        // Y = LN(A + P)
        addln_kernel<<<MROWS, 256, 0, stream>>>(R1f, Pf, g1_l, be1_l, Yf, Y_bf);

        // F1 = relu(Y @ W1 + b1) (bf16 out), 512 blocks
        gemm_mfma<128, 128, 2, 0, 1, 1><<<dim3(16, 32), 256, 0, stream>>>(
            Y_bf, W1T, b1_l, F1, MROWS, 2048, 512);

        // F2 = F1 @ W2 + b2 (fp32 out), 64x64 tiles -> 512 blocks
        gemm_mfma<64, 64, 2, 1, 1, 0><<<dim3(8, 64), 256, 0, stream>>>(
            F1, W2T, b2_l, R1f, MROWS, 512, 2048);

        // x_next = LN(Y + F2)
        float* dstf = (l == LAYERS - 1) ? out : R1f;
        addln_kernel<<<MROWS, 256, 0, stream>>>(Yf, R1f, g2_l, be2_l, dstf, A_bf);
    }
}

// Round 10
// 451.548 us; speedup vs baseline: 1.3093x; 1.0343x over previous
//
#include <hip/hip_runtime.h>
#include <hip/hip_bf16.h>
#include <math.h>

#define LAYERS 2
#define HIDDEN 512
#define FFN_DIM 2048
#define HEADS 8
#define SLEN 2048
#define BSZ 2
#define MROWS 4096
#define ATT_SCALING 0.125f
#define LN_EPS 1e-5f
#define SCALE_BASE 512.0f
#define LOG2E 1.4426950408889634f

typedef unsigned short u16;
typedef unsigned int u32;
typedef __attribute__((ext_vector_type(8))) short bf16x8;   // 8 bf16 = 4 VGPR
typedef __attribute__((ext_vector_type(4))) float f32x4;

__device__ __forceinline__ float bf2f(u16 u) {
    union { u32 i; float f; } v; v.i = ((u32)u) << 16; return v.f;
}
__device__ __forceinline__ u16 f2bf(float f) {
    union { float f; u32 i; } v; v.f = f;
    u32 r = v.i + 0x7FFFu + ((v.i >> 16) & 1u);   // RNE
    return (u16)(r >> 16);
}
__device__ __forceinline__ u32 pk2bf(float a, float b) {   // packed RNE cvt
    union { __hip_bfloat162 h; u32 u; } v;
    v.h = __float22bfloat162_rn(make_float2(a, b));
    return v.u;
}
__device__ __forceinline__ void async16(const void* g, void* l) {
    __builtin_amdgcn_global_load_lds((const __attribute__((address_space(1))) void*)g,
                                     (__attribute__((address_space(3))) void*)l, 16, 0, 0);
}

// ---------------------------------------------------------------------------
// fp32 [K][N] -> bf16 [N][K] transpose (weights prep)
// ---------------------------------------------------------------------------
__global__ __launch_bounds__(256) void wtrans(const float* __restrict__ in,
                                              u16* __restrict__ out,
                                              int K, int N) {
    __shared__ float t[32][33];
    int tx = threadIdx.x & 31, ty = threadIdx.x >> 5;       // 32 x 8
    int k0 = blockIdx.y * 32, n0 = blockIdx.x * 32;
#pragma unroll
    for (int i = 0; i < 4; i++)
        t[ty + 8 * i][tx] = in[(size_t)(k0 + ty + 8 * i) * N + n0 + tx];
    __syncthreads();
#pragma unroll
    for (int i = 0; i < 4; i++)
        out[(size_t)(n0 + ty + 8 * i) * K + k0 + tx] = f2bf(t[tx][ty + 8 * i]);
}

// ---------------------------------------------------------------------------
// x fp32 -> residual fp32 copy + bf16 copy (float4 vectorized)
// ---------------------------------------------------------------------------
__global__ __launch_bounds__(256) void cvt_x(const float* __restrict__ x,
                                             float* __restrict__ Af,
                                             u16* __restrict__ Ab) {
    int i = (blockIdx.x * 256 + threadIdx.x) * 4;
    float4 v = *(const float4*)(x + i);
    *(float4*)(Af + i) = v;
    uint2 p;
    p.x = pk2bf(v.x, v.y);
    p.y = pk2bf(v.z, v.w);
    *(uint2*)(Ab + i) = p;
}

// ---------------------------------------------------------------------------
// xPos cos/sin table: tab[s*32+j] = (cos*scale, sin*scale)
// ---------------------------------------------------------------------------
__global__ __launch_bounds__(256) void xpos_table(float2* __restrict__ tab) {
    int idx = blockIdx.x * 256 + threadIdx.x;   // 2048*32 = 65536
    int j = idx & 31;
    int s = idx >> 5;
    float base = (2.0f * j + 0.4f * 64.0f) / (1.4f * 64.0f);
    float pos = (float)(s - 1024);
    float scale = powf(base, pos / SCALE_BASE);
    float inv_freq = powf(10000.0f, -(float)j / 32.0f);
    float ang = (float)s * inv_freq;
    tab[idx] = make_float2(cosf(ang) * scale, sinf(ang) * scale);
}

// ---------------------------------------------------------------------------
// xPos applied in-place to Q (cols h*64+..) and K (cols 512+h*64+..) of QKV
// bf16, packed u32 accesses. Q additionally scaled by LOG2E (exp2 softmax).
// ---------------------------------------------------------------------------
__global__ __launch_bounds__(256) void xpos_kernel(u16* __restrict__ QKV,
                                                   const float2* __restrict__ tab) {
    int idx = blockIdx.x * 256 + threadIdx.x;   // 2^20
    int j = idx & 31;
    int h = (idx >> 5) & 7;
    int s = (idx >> 8) & 2047;
    int b = idx >> 19;

    float2 cssn = tab[s * 32 + j];
    float cs = cssn.x, sn = cssn.y;

    size_t off = (size_t)(b * SLEN + s) * 2048 + h * 64 + 2 * j;
    u32* pq = (u32*)(QKV + off);
    u32* pk = (u32*)(QKV + off + 512);

    u32 qv = *pq;
    float q0 = bf2f((u16)(qv & 0xffff)), q1 = bf2f((u16)(qv >> 16));
    *pq = pk2bf((q0 * cs - q1 * sn) * LOG2E, (q1 * cs + q0 * sn) * LOG2E);

    u32 kv = *pk;
    float k0 = bf2f((u16)(kv & 0xffff)), k1 = bf2f((u16)(kv >> 16));
    *pk = pk2bf(k0 * cs - k1 * sn, k1 * cs + k0 * sn);
}

// ---------------------------------------------------------------------------
// V section of QKV -> VT[(b*8+h)*128 + v][s]  (bf16 -> bf16 transpose)
// ---------------------------------------------------------------------------
__global__ __launch_bounds__(256) void vtrans(const u16* __restrict__ QKV,
                                              u16* __restrict__ VT) {
    __shared__ u16 t[64][65];
    int b = blockIdx.z >> 3, h = blockIdx.z & 7;
    int s0 = blockIdx.x * 64, v0 = blockIdx.y * 64;
    int tid = threadIdx.x;
#pragma unroll
    for (int i = 0; i < 16; i++) {
        int e = tid + i * 256; int r = e >> 6, c = e & 63;      // r: s, c: v
        t[r][c] = QKV[(size_t)(b * SLEN + s0 + r) * 2048 + 1024 + h * 128 + v0 + c];
    }
    __syncthreads();
#pragma unroll
    for (int i = 0; i < 16; i++) {
        int e = tid + i * 256; int r = e >> 6, c = e & 63;      // r: v, c: s
        VT[(size_t)((b * 8 + h) * 128 + v0 + r) * 2048 + s0 + c] = t[c][r];
    }
}

// ---------------------------------------------------------------------------
// MFMA GEMM, software-pipelined, BK=templated (64), optional 2-way split-K
// writing fp32 partials to C0/C1 (bias added by split 0 only).
// C[M,N] = A[M,K] @ W[K,N], W given as WT[N][K] (both bf16).
// ---------------------------------------------------------------------------
template <int BM, int BN, int BK, int WM, int OUTF32, int BIAS, int RELU, int NSPLIT>
__global__ __launch_bounds__(256) void gemm_mfma(const u16* __restrict__ A,
                                                 const u16* __restrict__ WT,
                                                 const float* __restrict__ bias,
                                                 void* __restrict__ C0,
                                                 void* __restrict__ C1,
                                                 int M, int N, int K) {
    constexpr int WN  = 4 / WM;
    constexpr int AM  = BM / (WM * 16);
    constexpr int AN  = BN / (WN * 16);
    constexpr int KO  = BK / 32;
    constexpr int AIT = BM * BK / 2048;
    constexpr int BIT = BN * BK / 2048;
    constexpr int KB8 = BK / 8;

    __shared__ u16 As[2][BM * BK];
    __shared__ u16 Bs[2][BN * BK];

    const int tid  = threadIdx.x;
    const int wave = tid >> 6;
    const int lane = tid & 63;
    const int quad = lane >> 4;
    const int l15  = lane & 15;
    const int wm = wave % WM;
    const int wn = wave / WM;

    const int tm = blockIdx.y * BM;
    const int tn = blockIdx.x * BN;
    const int z  = (NSPLIT > 1) ? blockIdx.z : 0;
    const int Ksub = K / NSPLIT;
    const int k0g  = z * Ksub;

    auto issue = [&](int kt, int buf) {
#pragma unroll
        for (int it = 0; it < AIT; it++) {
            int cid = it * 256 + tid;
            async16(A + (size_t)(tm + cid / KB8) * K + k0g + kt + (cid % KB8) * 8,
                    (char*)As[buf] + (it * 256 + wave * 64) * 16);
        }
#pragma unroll
        for (int it = 0; it < BIT; it++) {
            int cid = it * 256 + tid;
            async16(WT + (size_t)(tn + cid / KB8) * K + k0g + kt + (cid % KB8) * 8,
                    (char*)Bs[buf] + (it * 256 + wave * 64) * 16);
        }
    };

    f32x4 acc[AM][AN];
#pragma unroll
    for (int i = 0; i < AM; i++)
#pragma unroll
        for (int j = 0; j < AN; j++) acc[i][j] = (f32x4){0.f, 0.f, 0.f, 0.f};

    const int nk = Ksub / BK;
    issue(0, 0);

    for (int t = 0; t < nk; t++) {
        __syncthreads();             // implicit vmcnt(0) drain: loads(t) done
        if (t + 1 < nk) issue((t + 1) * BK, (t + 1) & 1);
        const int buf = t & 1;

        bf16x8 af[KO][AM], bfr[KO][AN];
#pragma unroll
        for (int ko = 0; ko < KO; ko++) {
#pragma unroll
            for (int i = 0; i < AM; i++)
                af[ko][i] = *(const bf16x8*)((const char*)As[buf] +
                    (((wm * (AM * 16) + i * 16 + l15) * KB8) + ko * 4 + quad) * 16);
#pragma unroll
            for (int j = 0; j < AN; j++)
                bfr[ko][j] = *(const bf16x8*)((const char*)Bs[buf] +
                    (((wn * (AN * 16) + j * 16 + l15) * KB8) + ko * 4 + quad) * 16);
        }
#pragma unroll
        for (int ko = 0; ko < KO; ko++)
#pragma unroll
            for (int i = 0; i < AM; i++)
#pragma unroll
                for (int j = 0; j < AN; j++)
                    acc[i][j] = __builtin_amdgcn_mfma_f32_16x16x32_bf16(
                        af[ko][i], bfr[ko][j], acc[i][j], 0, 0, 0);
    }

    void* Cout = (NSPLIT > 1 && z) ? C1 : C0;
#pragma unroll
    for (int i = 0; i < AM; i++) {
#pragma unroll
        for (int j = 0; j < AN; j++) {
            int col = tn + wn * (AN * 16) + j * 16 + l15;
            float bv = (BIAS && z == 0) ? bias[col] : 0.0f;
#pragma unroll
            for (int r = 0; r < 4; r++) {
                int row = tm + wm * (AM * 16) + i * 16 + quad * 4 + r;
                float v = acc[i][j][r] + bv;
                if (RELU) v = fmaxf(v, 0.0f);
                if (OUTF32) ((float*)Cout)[(size_t)row * N + col] = v;
                else        ((u16*)Cout)[(size_t)row * N + col] = f2bf(v);
            }
        }
    }
}

// ---------------------------------------------------------------------------
// MFMA flash attention v5 (unchanged from round 9): 128-q tile, 2 chains/wave,
// 2-way split-K, XCD-swizzled grid (h, qtile, b*2+split), transposed S and PV.
// ---------------------------------------------------------------------------
__global__ __launch_bounds__(256, 2) void flash_attn_mfma(const u16* __restrict__ QKV,
                                                          const u16* __restrict__ VT,
                                                          u16* __restrict__ OP0,
                                                          u16* __restrict__ OP1,
                                                          float2* __restrict__ ML) {
    const int h  = blockIdx.x;           // XCD swizzle: x = head
    const int q0 = blockIdx.y * 128;
    const int bz = blockIdx.z;           // b*2 + split
    const int b  = bz >> 1;
    const int split = bz & 1;
    const int tid  = threadIdx.x;
    const int wave = tid >> 6;
    const int lane = tid & 63;
    const int quad = lane >> 4;
    const int l15  = lane & 15;

    __shared__ u16 Ks[2][64 * 64];   // 2 x 8 KB
    __shared__ u16 Vs[2][128 * 64];  // 2 x 16 KB   (48 KB total)

    auto issueKV = [&](int kt, int buf) {
#pragma unroll
        for (int it = 0; it < 2; it++) {
            int cid = it * 256 + tid;
            int c = cid >> 8, p = cid & 255;
            async16(QKV + (size_t)(b * SLEN + kt + (p >> 2)) * 2048 + 512 + h * 64 +
                        c * 32 + (p & 3) * 8,
                    (char*)Ks[buf] + (it * 256 + wave * 64) * 16);
        }
#pragma unroll
        for (int it = 0; it < 4; it++) {
            int cid = it * 256 + tid;
            int c = cid >> 9, p = cid & 511;
            async16(VT + (size_t)((b * 8 + h) * 128 + (p >> 2)) * 2048 + kt +
                        c * 32 + (p & 3) * 8,
                    (char*)Vs[buf] + (it * 256 + wave * 64) * 16);
        }
    };

    bf16x8 qf[2][2];
#pragma unroll
    for (int cn = 0; cn < 2; cn++) {
        const u16* p = QKV + (size_t)(b * SLEN + q0 + cn * 64 + wave * 16 + l15) * 2048 +
                       h * 64 + quad * 8;
        qf[cn][0] = *(const bf16x8*)p;
        qf[cn][1] = *(const bf16x8*)(p + 32);
    }

    f32x4 o_acc[2][8];
#pragma unroll
    for (int cn = 0; cn < 2; cn++)
#pragma unroll
        for (int t = 0; t < 8; t++) o_acc[cn][t] = (f32x4){0.f, 0.f, 0.f, 0.f};
    float m[2] = {-1e30f, -1e30f};
    float l[2] = {0.f, 0.f};

    const int kb0 = split * 1024;
    issueKV(kb0, 0);

    for (int ti = 0; ti < 16; ti++) {
        __syncthreads();                 // implicit vmcnt(0): tiles(ti) landed
        if (ti + 1 < 16) issueKV(kb0 + (ti + 1) * 64, (ti + 1) & 1);
        const int buf = ti & 1;

        // S^T for both chains; K fragments read once, shared
        f32x4 st[2][4];
#pragma unroll
        for (int cn = 0; cn < 2; cn++)
#pragma unroll
            for (int t = 0; t < 4; t++) st[cn][t] = (f32x4){0.f, 0.f, 0.f, 0.f};
#pragma unroll
        for (int c = 0; c < 2; c++)
#pragma unroll
            for (int t = 0; t < 4; t++) {
                bf16x8 kb = *(const bf16x8*)((const char*)Ks[buf] + c * 4096 +
                             ((t * 16 + l15) * 4 + quad) * 16);
                st[0][t] = __builtin_amdgcn_mfma_f32_16x16x32_bf16(kb, qf[0][c],
                                                                   st[0][t], 0, 0, 0);
                st[1][t] = __builtin_amdgcn_mfma_f32_16x16x32_bf16(kb, qf[1][c],
                                                                   st[1][t], 0, 0, 0);
            }

        // softmax, both chains stepwise-interleaved (shared waitcnt windows)
        float mx[2], tp[2];
#pragma unroll
        for (int cn = 0; cn < 2; cn++) {
            float v = -1e30f;
#pragma unroll
            for (int t = 0; t < 4; t++)
#pragma unroll
                for (int r = 0; r < 4; r++) v = fmaxf(v, st[cn][t][r]);
            mx[cn] = v;
        }
        tp[0] = __shfl_xor(mx[0], 16, 64); tp[1] = __shfl_xor(mx[1], 16, 64);
        mx[0] = fmaxf(mx[0], tp[0]);       mx[1] = fmaxf(mx[1], tp[1]);
        tp[0] = __shfl_xor(mx[0], 32, 64); tp[1] = __shfl_xor(mx[1], 32, 64);
        mx[0] = fmaxf(mx[0], tp[0]);       mx[1] = fmaxf(mx[1], tp[1]);

        float alpha[2], ls[2];
        u32 pp[2][4][2];
#pragma unroll
        for (int cn = 0; cn < 2; cn++) {
            float mnew = fmaxf(m[cn], mx[cn]);
            alpha[cn] = exp2f(m[cn] - mnew);
            float s = 0.f;
#pragma unroll
            for (int t = 0; t < 4; t++)
#pragma unroll
                for (int pr = 0; pr < 2; pr++) {
                    float p0 = exp2f(st[cn][t][2 * pr] - mnew);
                    float p1 = exp2f(st[cn][t][2 * pr + 1] - mnew);
                    s += p0 + p1;
                    pp[cn][t][pr] = pk2bf(p0, p1);
                }
            ls[cn] = s;
            m[cn] = mnew;
        }
        tp[0] = __shfl_xor(ls[0], 16, 64); tp[1] = __shfl_xor(ls[1], 16, 64);
        ls[0] += tp[0];                    ls[1] += tp[1];
        tp[0] = __shfl_xor(ls[0], 32, 64); tp[1] = __shfl_xor(ls[1], 32, 64);
        ls[0] += tp[0];                    ls[1] += tp[1];
        l[0] = l[0] * alpha[0] + ls[0];
        l[1] = l[1] * alpha[1] + ls[1];

        // rescale: o_acc is O^T[v][q=l15]; alpha lives at q=l15 -> plain mul
#pragma unroll
        for (int cn = 0; cn < 2; cn++)
#pragma unroll
            for (int t = 0; t < 8; t++)
#pragma unroll
                for (int r = 0; r < 4; r++) o_acc[cn][t][r] *= alpha[cn];

        // PV (transposed): gather P^T B-fragments via shfl, A = V^T from LDS
#pragma unroll
        for (int c = 0; c < 2; c++) {
            union { u32 u[4]; bf16x8 v; } pu[2];
#pragma unroll
            for (int j2 = 0; j2 < 4; j2++) {
                int src = (2 * (quad & 1) + (j2 >> 1)) * 16 + l15;
                u32 g0a = (u32)__shfl((int)pp[0][2 * c][j2 & 1], src, 64);
                u32 g1a = (u32)__shfl((int)pp[0][2 * c + 1][j2 & 1], src, 64);
                u32 g0b = (u32)__shfl((int)pp[1][2 * c][j2 & 1], src, 64);
                u32 g1b = (u32)__shfl((int)pp[1][2 * c + 1][j2 & 1], src, 64);
                pu[0].u[j2] = (quad & 2) ? g1a : g0a;
                pu[1].u[j2] = (quad & 2) ? g1b : g0b;
            }
#pragma unroll
            for (int t = 0; t < 8; t++) {
                bf16x8 vb = *(const bf16x8*)((const char*)Vs[buf] + c * 8192 +
                             ((t * 16 + l15) * 4 + quad) * 16);
                o_acc[0][t] = __builtin_amdgcn_mfma_f32_16x16x32_bf16(vb, pu[0].v,
                                                                      o_acc[0][t], 0, 0, 0);
                o_acc[1][t] = __builtin_amdgcn_mfma_f32_16x16x32_bf16(vb, pu[1].v,
                                                                      o_acc[1][t], 0, 0, 0);
            }
        }
    }

    // epilogue: o_acc[cn][t][r] = O^T[v = t*16+quad*4+r][q = l15], packed u32
    u16* OP = split ? OP1 : OP0;
#pragma unroll
    for (int cn = 0; cn < 2; cn++) {
        if (quad == 0)
            ML[((size_t)(split * 2 + b) * 8 + h) * 2048 + q0 + cn * 64 + wave * 16 + l15] =
                make_float2(m[cn], l[cn]);
        size_t rowbase = ((size_t)(b * SLEN + q0 + cn * 64 + wave * 16 + l15)) * 1024 +
                         h * 128;
#pragma unroll
        for (int t = 0; t < 8; t++)
#pragma unroll
            for (int rp = 0; rp < 2; rp++)
                *(u32*)(OP + rowbase + t * 16 + quad * 4 + 2 * rp) =
                    pk2bf(o_acc[cn][t][2 * rp], o_acc[cn][t][2 * rp + 1]);
    }
}

// ---------------------------------------------------------------------------
// Merge the two split-K partials (8 elems/thread, uint4 vectorized):
// out = SCALING * (O0*w0 + O1*w1) / L
// ---------------------------------------------------------------------------
__global__ __launch_bounds__(256) void attn_combine(const u16* __restrict__ P0,
                                                    const u16* __restrict__ P1,
                                                    const float2* __restrict__ ML,
                                                    u16* __restrict__ AT) {
    int idx = (blockIdx.x * 256 + threadIdx.x) * 8;   // 4096*1024 total
    int hv = idx & 1023;
    int row = idx >> 10;                        // b*2048 + q
    int h = hv >> 7;
    int b = row >> 11, q = row & 2047;
    float2 ml0 = ML[((size_t)(0 + b) * 8 + h) * 2048 + q];
    float2 ml1 = ML[((size_t)(2 + b) * 8 + h) * 2048 + q];
    float M = fmaxf(ml0.x, ml1.x);
    float w0 = exp2f(ml0.x - M), w1 = exp2f(ml1.x - M);
    float L = ml0.y * w0 + ml1.y * w1;
    float sc = ATT_SCALING / L;
    w0 *= sc; w1 *= sc;

    uint4 a = *(const uint4*)(P0 + idx);
    uint4 c = *(const uint4*)(P1 + idx);
    uint4 o;
    u32 au[4] = {a.x, a.y, a.z, a.w};
    u32 cu[4] = {c.x, c.y, c.z, c.w};
    u32 ou[4];
#pragma unroll
    for (int k = 0; k < 4; k++) {
        float r0 = bf2f((u16)(au[k] & 0xffff)) * w0 + bf2f((u16)(cu[k] & 0xffff)) * w1;
        float r1 = bf2f((u16)(au[k] >> 16)) * w0 + bf2f((u16)(cu[k] >> 16)) * w1;
        ou[k] = pk2bf(r0, r1);
    }
    o.x = ou[0]; o.y = ou[1]; o.z = ou[2]; o.w = ou[3];
    *(uint4*)(AT + idx) = o;
}

// ---------------------------------------------------------------------------
// LN(X + R0 + R1) * g + be : fp32 in, fp32 + bf16 out (one block per row)
// ---------------------------------------------------------------------------
__global__ __launch_bounds__(256) void addln_kernel(const float* __restrict__ X,
                                                    const float* __restrict__ R0,
                                                    const float* __restrict__ R1,
                                                    const float* __restrict__ g,
                                                    const float* __restrict__ be,
                                                    float* __restrict__ dstf,
                                                    u16* __restrict__ dstb) {
    const int row = blockIdx.x;
    const int tid = threadIdx.x;
    __shared__ float red[256];
    size_t off = (size_t)row * HIDDEN;
    float v0 = X[off + tid] + R0[off + tid] + R1[off + tid];
    float v1 = X[off + tid + 256] + R0[off + tid + 256] + R1[off + tid + 256];
    red[tid] = v0 + v1;
    __syncthreads();
    for (int s = 128; s > 0; s >>= 1) { if (tid < s) red[tid] += red[tid + s]; __syncthreads(); }
    float mu = red[0] * (1.0f / HIDDEN);
    __syncthreads();
    float d0 = v0 - mu, d1 = v1 - mu;
    red[tid] = d0 * d0 + d1 * d1;
    __syncthreads();
    for (int s = 128; s > 0; s >>= 1) { if (tid < s) red[tid] += red[tid + s]; __syncthreads(); }
    float rstd = rsqrtf(red[0] * (1.0f / HIDDEN) + LN_EPS);
    float o0 = d0 * rstd * g[tid] + be[tid];
    float o1 = d1 * rstd * g[tid + 256] + be[tid + 256];
    dstf[off + tid] = o0;
    dstf[off + tid + 256] = o1;
    dstb[off + tid] = f2bf(o0);
    dstb[off + tid + 256] = f2bf(o1);
}

// ---------------------------------------------------------------------------
extern "C" void kernel_launch(void* const* d_in, const int* in_sizes, int n_in,
                              void* d_out, int out_size, void* d_ws, size_t ws_size,
                              hipStream_t stream) {
    const float* x   = (const float*)d_in[0];
    const float* Wq  = (const float*)d_in[1];
    const float* Wk  = (const float*)d_in[2];
    const float* Wv  = (const float*)d_in[3];
    const float* Wo  = (const float*)d_in[4];
    const float* W1  = (const float*)d_in[5];
    const float* b1  = (const float*)d_in[6];
    const float* W2  = (const float*)d_in[7];
    const float* b2  = (const float*)d_in[8];
    const float* g1  = (const float*)d_in[9];
    const float* be1 = (const float*)d_in[10];
    const float* g2  = (const float*)d_in[11];
    const float* be2 = (const float*)d_in[12];
    float* out = (float*)d_out;

    // Workspace (63 MB). Per-layer liveness (order: QKV,xpos,vtrans,flash,
    // combine,Wo,addln1,W1,W2,addln2):
    //  0-8   : R1f residual -> F2a (W2 split0, fp32; addln1 read R1f first)
    //  8-16  : VTg (flash) -> Yf (addln1 write, addln2 read)
    //  16-24 : OP1 (flash split1) -> PfA (Wo split0 fp32) -> F2b (W2 split1)
    //  24-40 : QKV bf16 -> PfB at 24-32 (Wo split1 fp32) -> F1 bf16
    //  40-48 : A_bf at 40-44 (QKV gemm in) -> OP0/AT -> Y_bf 40-44 -> A_bf 40-44
    //  48-62 : bf16 transposed weights
    //  62-63 : xtab ; ML
    const size_t MB = 1u << 20;
    char* w = (char*)d_ws;
    float*  R1f  = (float*)(w);
    float*  F2a  = (float*)(w);
    u16*    VTg  = (u16*)(w + 8 * MB);
    float*  Yf   = (float*)(w + 8 * MB);
    u16*    OP1  = (u16*)(w + 16 * MB);
    float*  PfA  = (float*)(w + 16 * MB);
    float*  F2b  = (float*)(w + 16 * MB);
    u16*    QKV  = (u16*)(w + 24 * MB);
    float*  PfB  = (float*)(w + 24 * MB);
    u16*    F1   = (u16*)(w + 24 * MB);
    u16*    A_bf = (u16*)(w + 40 * MB);
    u16*    OP0  = (u16*)(w + 40 * MB);
    u16*    AT   = (u16*)(w + 40 * MB);
    u16*    Y_bf = (u16*)(w + 40 * MB);
    float2* xtab = (float2*)(w + 62 * MB);
    float2* ML   = (float2*)(w + 62 * MB + 512 * 1024);

    cvt_x<<<MROWS * HIDDEN / 1024, 256, 0, stream>>>(x, R1f, A_bf);
    xpos_table<<<256, 256, 0, stream>>>(xtab);

    for (int l = 0; l < LAYERS; l++) {
        u16* WqkvT = (u16*)(w + 48 * MB + (size_t)l * 2 * MB);
        u16* WoT   = (u16*)(w + 52 * MB + (size_t)l * 1 * MB);
        u16* W1T   = (u16*)(w + 54 * MB + (size_t)l * 2 * MB);
        u16* W2T   = (u16*)(w + 58 * MB + (size_t)l * 2 * MB);
        wtrans<<<dim3(16, 16), 256, 0, stream>>>(Wq + (size_t)l * 512 * 512,  WqkvT,              512, 512);
        wtrans<<<dim3(16, 16), 256, 0, stream>>>(Wk + (size_t)l * 512 * 512,  WqkvT + 512 * 512,  512, 512);
        wtrans<<<dim3(32, 16), 256, 0, stream>>>(Wv + (size_t)l * 512 * 1024, WqkvT + 1024 * 512, 512, 1024);
        wtrans<<<dim3(16, 32), 256, 0, stream>>>(Wo + (size_t)l * 1024 * 512, WoT,                1024, 512);
        wtrans<<<dim3(64, 16), 256, 0, stream>>>(W1 + (size_t)l * 512 * 2048, W1T,                512, 2048);
        wtrans<<<dim3(16, 64), 256, 0, stream>>>(W2 + (size_t)l * 2048 * 512, W2T,                2048, 512);
    }

    for (int l = 0; l < LAYERS; l++) {
        u16* WqkvT = (u16*)(w + 48 * MB + (size_t)l * 2 * MB);
        u16* WoT   = (u16*)(w + 52 * MB + (size_t)l * 1 * MB);
        u16* W1T   = (u16*)(w + 54 * MB + (size_t)l * 2 * MB);
        u16* W2T   = (u16*)(w + 58 * MB + (size_t)l * 2 * MB);
        const float* b1_l  = b1 + (size_t)l * FFN_DIM;
        const float* b2_l  = b2 + (size_t)l * HIDDEN;
        const float* g1_l  = g1 + (size_t)l * HIDDEN;
        const float* be1_l = be1 + (size_t)l * HIDDEN;
        const float* g2_l  = g2 + (size_t)l * HIDDEN;
        const float* be2_l = be2 + (size_t)l * HIDDEN;

        // QKV = A_bf @ [Wq|Wk|Wv]  (bf16 out), 128x128xBK64, 512 blocks
        gemm_mfma<128, 128, 64, 2, 0, 0, 0, 1><<<dim3(16, 32), 256, 0, stream>>>(
            A_bf, WqkvT, nullptr, QKV, nullptr, MROWS, 2048, 512);

        xpos_kernel<<<4096, 256, 0, stream>>>(QKV, xtab);
        vtrans<<<dim3(32, 2, 16), 256, 0, stream>>>(QKV, VTg);

        // flash attention: XCD-swizzled grid (h, qtile, b*2+split)
        flash_attn_mfma<<<dim3(8, 16, 4), 256, 0, stream>>>(QKV, VTg, OP0, OP1, ML);
        attn_combine<<<MROWS * 1024 / 2048, 256, 0, stream>>>(OP0, OP1, ML, AT);

        // P = AT @ Wo: 128x64xBK64, 2-way split-K -> fp32 partials, 512 blocks
        gemm_mfma<128, 64, 64, 2, 1, 0, 0, 2><<<dim3(8, 32, 2), 256, 0, stream>>>(
            AT, WoT, nullptr, PfA, PfB, MROWS, 512, 1024);

        // Y = LN(A + P0 + P1)
        addln_kernel<<<MROWS, 256, 0, stream>>>(R1f, PfA, PfB, g1_l, be1_l, Yf, Y_bf);

        // F1 = relu(Y @ W1 + b1) (bf16 out), 128x128xBK64, 512 blocks
        gemm_mfma<128, 128, 64, 2, 0, 1, 1, 1><<<dim3(16, 32), 256, 0, stream>>>(
            Y_bf, W1T, b1_l, F1, nullptr, MROWS, 2048, 512);

        // F2 = F1 @ W2 + b2: 128x64xBK64, 2-way split-K -> fp32 partials
        gemm_mfma<128, 64, 64, 2, 1, 1, 0, 2><<<dim3(8, 32, 2), 256, 0, stream>>>(
            F1, W2T, b2_l, F2a, F2b, MROWS, 512, 2048);

        // x_next = LN(Y + F2a + F2b)
        float* dstf = (l == LAYERS - 1) ? out : R1f;
        addln_kernel<<<MROWS, 256, 0, stream>>>(Yf, F2a, F2b, g2_l, be2_l, dstf, A_bf);
    }
}

// Round 11
// 425.814 us; speedup vs baseline: 1.3885x; 1.0604x over previous
//
#include <hip/hip_runtime.h>
#include <hip/hip_bf16.h>
#include <math.h>

#define LAYERS 2
#define HIDDEN 512
#define FFN_DIM 2048
#define HEADS 8
#define SLEN 2048
#define BSZ 2
#define MROWS 4096
#define ATT_SCALING 0.125f
#define LN_EPS 1e-5f
#define SCALE_BASE 512.0f
#define LOG2E 1.4426950408889634f

typedef unsigned short u16;
typedef unsigned int u32;
typedef __attribute__((ext_vector_type(8))) short bf16x8;   // 8 bf16 = 4 VGPR
typedef __attribute__((ext_vector_type(4))) float f32x4;

__device__ __forceinline__ float bf2f(u16 u) {
    union { u32 i; float f; } v; v.i = ((u32)u) << 16; return v.f;
}
__device__ __forceinline__ u16 f2bf(float f) {
    union { float f; u32 i; } v; v.f = f;
    u32 r = v.i + 0x7FFFu + ((v.i >> 16) & 1u);   // RNE
    return (u16)(r >> 16);
}
__device__ __forceinline__ u32 pk2bf(float a, float b) {   // packed RNE cvt
    union { __hip_bfloat162 h; u32 u; } v;
    v.h = __float22bfloat162_rn(make_float2(a, b));
    return v.u;
}
__device__ __forceinline__ void async16(const void* g, void* l) {
    __builtin_amdgcn_global_load_lds((const __attribute__((address_space(1))) void*)g,
                                     (__attribute__((address_space(3))) void*)l, 16, 0, 0);
}

// ---------------------------------------------------------------------------
// Fused prep: all 12 weight transposes (fp32 [K][N] -> bf16 [N][K]) +
// x fp32 -> (fp32 residual, bf16) + xpos cos/sin table. One dispatch.
// Block ranges: [0,7168) wtrans, [7168,9216) cvt_x, [9216,9472) xpos_table.
// ---------------------------------------------------------------------------
__global__ __launch_bounds__(256) void prep_kernel(const float* __restrict__ x,
                                                   const float* __restrict__ Wq,
                                                   const float* __restrict__ Wk,
                                                   const float* __restrict__ Wv,
                                                   const float* __restrict__ Wo,
                                                   const float* __restrict__ W1,
                                                   const float* __restrict__ W2,
                                                   char* __restrict__ w,
                                                   float* __restrict__ Af,
                                                   u16* __restrict__ Ab,
                                                   float2* __restrict__ tab) {
    const size_t MB1 = 1u << 20;
    const int bid = blockIdx.x;
    const int tid = threadIdx.x;
    __shared__ float t[32][33];

    if (bid < 7168) {
        int l = bid / 3584;
        int tt = bid % 3584;
        u16* WqkvT = (u16*)(w + 48 * MB1 + (size_t)l * 2 * MB1);
        u16* WoT   = (u16*)(w + 52 * MB1 + (size_t)l * 1 * MB1);
        u16* W1T   = (u16*)(w + 54 * MB1 + (size_t)l * 2 * MB1);
        u16* W2T   = (u16*)(w + 58 * MB1 + (size_t)l * 2 * MB1);
        const float* src; u16* dst; int K, N, tix;
        if (tt < 256)       { src = Wq + (size_t)l * 512 * 512;  dst = WqkvT;              K = 512;  N = 512;  tix = tt; }
        else if (tt < 512)  { src = Wk + (size_t)l * 512 * 512;  dst = WqkvT + 512 * 512;  K = 512;  N = 512;  tix = tt - 256; }
        else if (tt < 1024) { src = Wv + (size_t)l * 512 * 1024; dst = WqkvT + 1024 * 512; K = 512;  N = 1024; tix = tt - 512; }
        else if (tt < 1536) { src = Wo + (size_t)l * 1024 * 512; dst = WoT;                K = 1024; N = 512;  tix = tt - 1024; }
        else if (tt < 2560) { src = W1 + (size_t)l * 512 * 2048; dst = W1T;                K = 512;  N = 2048; tix = tt - 1536; }
        else                { src = W2 + (size_t)l * 2048 * 512; dst = W2T;                K = 2048; N = 512;  tix = tt - 2560; }
        int ntx = N >> 5;
        int n0 = (tix % ntx) * 32, k0 = (tix / ntx) * 32;
        int tx = tid & 31, ty = tid >> 5;
#pragma unroll
        for (int i = 0; i < 4; i++)
            t[ty + 8 * i][tx] = src[(size_t)(k0 + ty + 8 * i) * N + n0 + tx];
        __syncthreads();
#pragma unroll
        for (int i = 0; i < 4; i++)
            dst[(size_t)(n0 + ty + 8 * i) * K + k0 + tx] = f2bf(t[tx][ty + 8 * i]);
    } else if (bid < 9216) {
        int i = ((bid - 7168) * 256 + tid) * 4;
        float4 v = *(const float4*)(x + i);
        *(float4*)(Af + i) = v;
        uint2 p;
        p.x = pk2bf(v.x, v.y);
        p.y = pk2bf(v.z, v.w);
        *(uint2*)(Ab + i) = p;
    } else {
        int idx = (bid - 9216) * 256 + tid;     // 65536 entries
        int j = idx & 31;
        int s = idx >> 5;
        float base = (2.0f * j + 0.4f * 64.0f) / (1.4f * 64.0f);
        float pos = (float)(s - 1024);
        float scale = powf(base, pos / SCALE_BASE);
        float inv_freq = powf(10000.0f, -(float)j / 32.0f);
        float ang = (float)s * inv_freq;
        tab[idx] = make_float2(cosf(ang) * scale, sinf(ang) * scale);
    }
}

// ---------------------------------------------------------------------------
// Fused xPos (in-place on Q,K cols of QKV; Q scaled by LOG2E) + V transpose
// (V cols of QKV -> VT) — column-disjoint, no intra-kernel ordering needed.
// Block ranges: [0,4096) xpos, [4096,5120) vtrans.
// ---------------------------------------------------------------------------
__global__ __launch_bounds__(256) void xpos_vtrans(u16* __restrict__ QKV,
                                                   const float2* __restrict__ tab,
                                                   u16* __restrict__ VT) {
    const int bid = blockIdx.x;
    const int tid = threadIdx.x;
    __shared__ u16 t[64][65];

    if (bid < 4096) {
        int idx = bid * 256 + tid;   // 2^20
        int j = idx & 31;
        int h = (idx >> 5) & 7;
        int s = (idx >> 8) & 2047;
        int b = idx >> 19;

        float2 cssn = tab[s * 32 + j];
        float cs = cssn.x, sn = cssn.y;

        size_t off = (size_t)(b * SLEN + s) * 2048 + h * 64 + 2 * j;
        u32* pq = (u32*)(QKV + off);
        u32* pk = (u32*)(QKV + off + 512);

        u32 qv = *pq;
        float q0 = bf2f((u16)(qv & 0xffff)), q1 = bf2f((u16)(qv >> 16));
        *pq = pk2bf((q0 * cs - q1 * sn) * LOG2E, (q1 * cs + q0 * sn) * LOG2E);

        u32 kv = *pk;
        float k0 = bf2f((u16)(kv & 0xffff)), k1 = bf2f((u16)(kv >> 16));
        *pk = pk2bf(k0 * cs - k1 * sn, k1 * cs + k0 * sn);
    } else {
        int v = bid - 4096;                 // 1024 blocks
        int bz = v & 15;                    // b*8 + h
        int vy = (v >> 4) & 1;              // v-tile
        int sx = v >> 5;                    // s-tile (32)
        int b = bz >> 3, h = bz & 7;
        int s0 = sx * 64, v0 = vy * 64;
#pragma unroll
        for (int i = 0; i < 16; i++) {
            int e = tid + i * 256; int r = e >> 6, c = e & 63;      // r: s, c: v
            t[r][c] = QKV[(size_t)(b * SLEN + s0 + r) * 2048 + 1024 + h * 128 + v0 + c];
        }
        __syncthreads();
#pragma unroll
        for (int i = 0; i < 16; i++) {
            int e = tid + i * 256; int r = e >> 6, c = e & 63;      // r: v, c: s
            VT[(size_t)((b * 8 + h) * 128 + v0 + r) * 2048 + s0 + c] = t[c][r];
        }
    }
}

// ---------------------------------------------------------------------------
// MFMA GEMM, software-pipelined, BK=64, optional 2-way split-K writing fp32
// partials to C0/C1 (bias added by split 0 only). WT is [N][K] bf16.
// ---------------------------------------------------------------------------
template <int BM, int BN, int BK, int WM, int OUTF32, int BIAS, int RELU, int NSPLIT>
__global__ __launch_bounds__(256) void gemm_mfma(const u16* __restrict__ A,
                                                 const u16* __restrict__ WT,
                                                 const float* __restrict__ bias,
                                                 void* __restrict__ C0,
                                                 void* __restrict__ C1,
                                                 int M, int N, int K) {
    constexpr int WN  = 4 / WM;
    constexpr int AM  = BM / (WM * 16);
    constexpr int AN  = BN / (WN * 16);
    constexpr int KO  = BK / 32;
    constexpr int AIT = BM * BK / 2048;
    constexpr int BIT = BN * BK / 2048;
    constexpr int KB8 = BK / 8;

    __shared__ u16 As[2][BM * BK];
    __shared__ u16 Bs[2][BN * BK];

    const int tid  = threadIdx.x;
    const int wave = tid >> 6;
    const int lane = tid & 63;
    const int quad = lane >> 4;
    const int l15  = lane & 15;
    const int wm = wave % WM;
    const int wn = wave / WM;

    const int tm = blockIdx.y * BM;
    const int tn = blockIdx.x * BN;
    const int z  = (NSPLIT > 1) ? blockIdx.z : 0;
    const int Ksub = K / NSPLIT;
    const int k0g  = z * Ksub;

    auto issue = [&](int kt, int buf) {
#pragma unroll
        for (int it = 0; it < AIT; it++) {
            int cid = it * 256 + tid;
            async16(A + (size_t)(tm + cid / KB8) * K + k0g + kt + (cid % KB8) * 8,
                    (char*)As[buf] + (it * 256 + wave * 64) * 16);
        }
#pragma unroll
        for (int it = 0; it < BIT; it++) {
            int cid = it * 256 + tid;
            async16(WT + (size_t)(tn + cid / KB8) * K + k0g + kt + (cid % KB8) * 8,
                    (char*)Bs[buf] + (it * 256 + wave * 64) * 16);
        }
    };

    f32x4 acc[AM][AN];
#pragma unroll
    for (int i = 0; i < AM; i++)
#pragma unroll
        for (int j = 0; j < AN; j++) acc[i][j] = (f32x4){0.f, 0.f, 0.f, 0.f};

    const int nk = Ksub / BK;
    issue(0, 0);

    for (int t = 0; t < nk; t++) {
        __syncthreads();             // implicit vmcnt(0) drain: loads(t) done
        if (t + 1 < nk) issue((t + 1) * BK, (t + 1) & 1);
        const int buf = t & 1;

        bf16x8 af[KO][AM], bfr[KO][AN];
#pragma unroll
        for (int ko = 0; ko < KO; ko++) {
#pragma unroll
            for (int i = 0; i < AM; i++)
                af[ko][i] = *(const bf16x8*)((const char*)As[buf] +
                    (((wm * (AM * 16) + i * 16 + l15) * KB8) + ko * 4 + quad) * 16);
#pragma unroll
            for (int j = 0; j < AN; j++)
                bfr[ko][j] = *(const bf16x8*)((const char*)Bs[buf] +
                    (((wn * (AN * 16) + j * 16 + l15) * KB8) + ko * 4 + quad) * 16);
        }
#pragma unroll
        for (int ko = 0; ko < KO; ko++)
#pragma unroll
            for (int i = 0; i < AM; i++)
#pragma unroll
                for (int j = 0; j < AN; j++)
                    acc[i][j] = __builtin_amdgcn_mfma_f32_16x16x32_bf16(
                        af[ko][i], bfr[ko][j], acc[i][j], 0, 0, 0);
    }

    void* Cout = (NSPLIT > 1 && z) ? C1 : C0;
#pragma unroll
    for (int i = 0; i < AM; i++) {
#pragma unroll
        for (int j = 0; j < AN; j++) {
            int col = tn + wn * (AN * 16) + j * 16 + l15;
            float bv = (BIAS && z == 0) ? bias[col] : 0.0f;
#pragma unroll
            for (int r = 0; r < 4; r++) {
                int row = tm + wm * (AM * 16) + i * 16 + quad * 4 + r;
                float v = acc[i][j][r] + bv;
                if (RELU) v = fmaxf(v, 0.0f);
                if (OUTF32) ((float*)Cout)[(size_t)row * N + col] = v;
                else        ((u16*)Cout)[(size_t)row * N + col] = f2bf(v);
            }
        }
    }
}

// ---------------------------------------------------------------------------
// MFMA flash attention v5 (unchanged from round 9/10): 128-q tile, 2 chains
// per wave, 2-way split-K, XCD-swizzled grid, transposed S and PV.
// ---------------------------------------------------------------------------
__global__ __launch_bounds__(256, 2) void flash_attn_mfma(const u16* __restrict__ QKV,
                                                          const u16* __restrict__ VT,
                                                          u16* __restrict__ OP0,
                                                          u16* __restrict__ OP1,
                                                          float2* __restrict__ ML) {
    const int h  = blockIdx.x;           // XCD swizzle: x = head
    const int q0 = blockIdx.y * 128;
    const int bz = blockIdx.z;           // b*2 + split
    const int b  = bz >> 1;
    const int split = bz & 1;
    const int tid  = threadIdx.x;
    const int wave = tid >> 6;
    const int lane = tid & 63;
    const int quad = lane >> 4;
    const int l15  = lane & 15;

    __shared__ u16 Ks[2][64 * 64];   // 2 x 8 KB
    __shared__ u16 Vs[2][128 * 64];  // 2 x 16 KB   (48 KB total)

    auto issueKV = [&](int kt, int buf) {
#pragma unroll
        for (int it = 0; it < 2; it++) {
            int cid = it * 256 + tid;
            int c = cid >> 8, p = cid & 255;
            async16(QKV + (size_t)(b * SLEN + kt + (p >> 2)) * 2048 + 512 + h * 64 +
                        c * 32 + (p & 3) * 8,
                    (char*)Ks[buf] + (it * 256 + wave * 64) * 16);
        }
#pragma unroll
        for (int it = 0; it < 4; it++) {
            int cid = it * 256 + tid;
            int c = cid >> 9, p = cid & 511;
            async16(VT + (size_t)((b * 8 + h) * 128 + (p >> 2)) * 2048 + kt +
                        c * 32 + (p & 3) * 8,
                    (char*)Vs[buf] + (it * 256 + wave * 64) * 16);
        }
    };

    bf16x8 qf[2][2];
#pragma unroll
    for (int cn = 0; cn < 2; cn++) {
        const u16* p = QKV + (size_t)(b * SLEN + q0 + cn * 64 + wave * 16 + l15) * 2048 +
                       h * 64 + quad * 8;
        qf[cn][0] = *(const bf16x8*)p;
        qf[cn][1] = *(const bf16x8*)(p + 32);
    }

    f32x4 o_acc[2][8];
#pragma unroll
    for (int cn = 0; cn < 2; cn++)
#pragma unroll
        for (int t = 0; t < 8; t++) o_acc[cn][t] = (f32x4){0.f, 0.f, 0.f, 0.f};
    float m[2] = {-1e30f, -1e30f};
    float l[2] = {0.f, 0.f};

    const int kb0 = split * 1024;
    issueKV(kb0, 0);

    for (int ti = 0; ti < 16; ti++) {
        __syncthreads();                 // implicit vmcnt(0): tiles(ti) landed
        if (ti + 1 < 16) issueKV(kb0 + (ti + 1) * 64, (ti + 1) & 1);
        const int buf = ti & 1;

        // S^T for both chains; K fragments read once, shared
        f32x4 st[2][4];
#pragma unroll
        for (int cn = 0; cn < 2; cn++)
#pragma unroll
            for (int t = 0; t < 4; t++) st[cn][t] = (f32x4){0.f, 0.f, 0.f, 0.f};
#pragma unroll
        for (int c = 0; c < 2; c++)
#pragma unroll
            for (int t = 0; t < 4; t++) {
                bf16x8 kb = *(const bf16x8*)((const char*)Ks[buf] + c * 4096 +
                             ((t * 16 + l15) * 4 + quad) * 16);
                st[0][t] = __builtin_amdgcn_mfma_f32_16x16x32_bf16(kb, qf[0][c],
                                                                   st[0][t], 0, 0, 0);
                st[1][t] = __builtin_amdgcn_mfma_f32_16x16x32_bf16(kb, qf[1][c],
                                                                   st[1][t], 0, 0, 0);
            }

        // softmax, both chains stepwise-interleaved (shared waitcnt windows)
        float mx[2], tp[2];
#pragma unroll
        for (int cn = 0; cn < 2; cn++) {
            float v = -1e30f;
#pragma unroll
            for (int t = 0; t < 4; t++)
#pragma unroll
                for (int r = 0; r < 4; r++) v = fmaxf(v, st[cn][t][r]);
            mx[cn] = v;
        }
        tp[0] = __shfl_xor(mx[0], 16, 64); tp[1] = __shfl_xor(mx[1], 16, 64);
        mx[0] = fmaxf(mx[0], tp[0]);       mx[1] = fmaxf(mx[1], tp[1]);
        tp[0] = __shfl_xor(mx[0], 32, 64); tp[1] = __shfl_xor(mx[1], 32, 64);
        mx[0] = fmaxf(mx[0], tp[0]);       mx[1] = fmaxf(mx[1], tp[1]);

        float alpha[2], ls[2];
        u32 pp[2][4][2];
#pragma unroll
        for (int cn = 0; cn < 2; cn++) {
            float mnew = fmaxf(m[cn], mx[cn]);
            alpha[cn] = exp2f(m[cn] - mnew);
            float s = 0.f;
#pragma unroll
            for (int t = 0; t < 4; t++)
#pragma unroll
                for (int pr = 0; pr < 2; pr++) {
                    float p0 = exp2f(st[cn][t][2 * pr] - mnew);
                    float p1 = exp2f(st[cn][t][2 * pr + 1] - mnew);
                    s += p0 + p1;
                    pp[cn][t][pr] = pk2bf(p0, p1);
                }
            ls[cn] = s;
            m[cn] = mnew;
        }
        tp[0] = __shfl_xor(ls[0], 16, 64); tp[1] = __shfl_xor(ls[1], 16, 64);
        ls[0] += tp[0];                    ls[1] += tp[1];
        tp[0] = __shfl_xor(ls[0], 32, 64); tp[1] = __shfl_xor(ls[1], 32, 64);
        ls[0] += tp[0];                    ls[1] += tp[1];
        l[0] = l[0] * alpha[0] + ls[0];
        l[1] = l[1] * alpha[1] + ls[1];

        // rescale: o_acc is O^T[v][q=l15]; alpha lives at q=l15 -> plain mul
#pragma unroll
        for (int cn = 0; cn < 2; cn++)
#pragma unroll
            for (int t = 0; t < 8; t++)
#pragma unroll
                for (int r = 0; r < 4; r++) o_acc[cn][t][r] *= alpha[cn];

        // PV (transposed): gather P^T B-fragments via shfl, A = V^T from LDS
#pragma unroll
        for (int c = 0; c < 2; c++) {
            union { u32 u[4]; bf16x8 v; } pu[2];
#pragma unroll
            for (int j2 = 0; j2 < 4; j2++) {
                int src = (2 * (quad & 1) + (j2 >> 1)) * 16 + l15;
                u32 g0a = (u32)__shfl((int)pp[0][2 * c][j2 & 1], src, 64);
                u32 g1a = (u32)__shfl((int)pp[0][2 * c + 1][j2 & 1], src, 64);
                u32 g0b = (u32)__shfl((int)pp[1][2 * c][j2 & 1], src, 64);
                u32 g1b = (u32)__shfl((int)pp[1][2 * c + 1][j2 & 1], src, 64);
                pu[0].u[j2] = (quad & 2) ? g1a : g0a;
                pu[1].u[j2] = (quad & 2) ? g1b : g0b;
            }
#pragma unroll
            for (int t = 0; t < 8; t++) {
                bf16x8 vb = *(const bf16x8*)((const char*)Vs[buf] + c * 8192 +
                             ((t * 16 + l15) * 4 + quad) * 16);
                o_acc[0][t] = __builtin_amdgcn_mfma_f32_16x16x32_bf16(vb, pu[0].v,
                                                                      o_acc[0][t], 0, 0, 0);
                o_acc[1][t] = __builtin_amdgcn_mfma_f32_16x16x32_bf16(vb, pu[1].v,
                                                                      o_acc[1][t], 0, 0, 0);
            }
        }
    }

    // epilogue: o_acc[cn][t][r] = O^T[v = t*16+quad*4+r][q = l15], packed u32
    u16* OP = split ? OP1 : OP0;
#pragma unroll
    for (int cn = 0; cn < 2; cn++) {
        if (quad == 0)
            ML[((size_t)(split * 2 + b) * 8 + h) * 2048 + q0 + cn * 64 + wave * 16 + l15] =
                make_float2(m[cn], l[cn]);
        size_t rowbase = ((size_t)(b * SLEN + q0 + cn * 64 + wave * 16 + l15)) * 1024 +
                         h * 128;
#pragma unroll
        for (int t = 0; t < 8; t++)
#pragma unroll
            for (int rp = 0; rp < 2; rp++)
                *(u32*)(OP + rowbase + t * 16 + quad * 4 + 2 * rp) =
                    pk2bf(o_acc[cn][t][2 * rp], o_acc[cn][t][2 * rp + 1]);
    }
}

// ---------------------------------------------------------------------------
// Merge the two split-K partials (8 elems/thread, uint4 vectorized):
// out = SCALING * (O0*w0 + O1*w1) / L
// ---------------------------------------------------------------------------
__global__ __launch_bounds__(256) void attn_combine(const u16* __restrict__ P0,
                                                    const u16* __restrict__ P1,
                                                    const float2* __restrict__ ML,
                                                    u16* __restrict__ AT) {
    int idx = (blockIdx.x * 256 + threadIdx.x) * 8;   // 4096*1024 total
    int hv = idx & 1023;
    int row = idx >> 10;                        // b*2048 + q
    int h = hv >> 7;
    int b = row >> 11, q = row & 2047;
    float2 ml0 = ML[((size_t)(0 + b) * 8 + h) * 2048 + q];
    float2 ml1 = ML[((size_t)(2 + b) * 8 + h) * 2048 + q];
    float M = fmaxf(ml0.x, ml1.x);
    float w0 = exp2f(ml0.x - M), w1 = exp2f(ml1.x - M);
    float L = ml0.y * w0 + ml1.y * w1;
    float sc = ATT_SCALING / L;
    w0 *= sc; w1 *= sc;

    uint4 a = *(const uint4*)(P0 + idx);
    uint4 c = *(const uint4*)(P1 + idx);
    uint4 o;
    u32 au[4] = {a.x, a.y, a.z, a.w};
    u32 cu[4] = {c.x, c.y, c.z, c.w};
    u32 ou[4];
#pragma unroll
    for (int k = 0; k < 4; k++) {
        float r0 = bf2f((u16)(au[k] & 0xffff)) * w0 + bf2f((u16)(cu[k] & 0xffff)) * w1;
        float r1 = bf2f((u16)(au[k] >> 16)) * w0 + bf2f((u16)(cu[k] >> 16)) * w1;
        ou[k] = pk2bf(r0, r1);
    }
    o.x = ou[0]; o.y = ou[1]; o.z = ou[2]; o.w = ou[3];
    *(uint4*)(AT + idx) = o;
}

// ---------------------------------------------------------------------------
// LN(X + R0 + R1) * g + be : fp32 in, fp32 + bf16 out, float2-vectorized.
// One block per 512-row; thread handles cols 2*tid, 2*tid+1.
// ---------------------------------------------------------------------------
__global__ __launch_bounds__(256) void addln_kernel(const float* __restrict__ X,
                                                    const float* __restrict__ R0,
                                                    const float* __restrict__ R1,
                                                    const float* __restrict__ g,
                                                    const float* __restrict__ be,
                                                    float* __restrict__ dstf,
                                                    u16* __restrict__ dstb) {
    const int row = blockIdx.x;
    const int tid = threadIdx.x;
    __shared__ float red[256];
    size_t off = (size_t)row * HIDDEN + 2 * tid;
    float2 a  = *(const float2*)(X + off);
    float2 r0 = *(const float2*)(R0 + off);
    float2 r1 = *(const float2*)(R1 + off);
    float v0 = a.x + r0.x + r1.x;
    float v1 = a.y + r0.y + r1.y;
    red[tid] = v0 + v1;
    __syncthreads();
    for (int s = 128; s > 0; s >>= 1) { if (tid < s) red[tid] += red[tid + s]; __syncthreads(); }
    float mu = red[0] * (1.0f / HIDDEN);
    __syncthreads();
    float d0 = v0 - mu, d1 = v1 - mu;
    red[tid] = d0 * d0 + d1 * d1;
    __syncthreads();
    for (int s = 128; s > 0; s >>= 1) { if (tid < s) red[tid] += red[tid + s]; __syncthreads(); }
    float rstd = rsqrtf(red[0] * (1.0f / HIDDEN) + LN_EPS);
    float2 gg = *(const float2*)(g + 2 * tid);
    float2 bb = *(const float2*)(be + 2 * tid);
    float o0 = d0 * rstd * gg.x + bb.x;
    float o1 = d1 * rstd * gg.y + bb.y;
    *(float2*)(dstf + off) = make_float2(o0, o1);
    *(u32*)(dstb + off) = pk2bf(o0, o1);
}

// ---------------------------------------------------------------------------
extern "C" void kernel_launch(void* const* d_in, const int* in_sizes, int n_in,
                              void* d_out, int out_size, void* d_ws, size_t ws_size,
                              hipStream_t stream) {
    const float* x   = (const float*)d_in[0];
    const float* Wq  = (const float*)d_in[1];
    const float* Wk  = (const float*)d_in[2];
    const float* Wv  = (const float*)d_in[3];
    const float* Wo  = (const float*)d_in[4];
    const float* W1  = (const float*)d_in[5];
    const float* b1  = (const float*)d_in[6];
    const float* W2  = (const float*)d_in[7];
    const float* b2  = (const float*)d_in[8];
    const float* g1  = (const float*)d_in[9];
    const float* be1 = (const float*)d_in[10];
    const float* g2  = (const float*)d_in[11];
    const float* be2 = (const float*)d_in[12];
    float* out = (float*)d_out;

    // Workspace (63 MB) — same liveness plan as round 10:
    //  0-8   : R1f residual -> F2a ;  8-16 : VTg -> Yf
    //  16-24 : OP1 -> PfA -> F2b  ; 24-40 : QKV -> PfB(24-32) -> F1
    //  40-48 : A_bf(40-44) -> OP0/AT -> Y_bf(40-44) -> A_bf
    //  48-62 : bf16 transposed weights ; 62-63 : xtab, ML
    const size_t MB = 1u << 20;
    char* w = (char*)d_ws;
    float*  R1f  = (float*)(w);
    float*  F2a  = (float*)(w);
    u16*    VTg  = (u16*)(w + 8 * MB);
    float*  Yf   = (float*)(w + 8 * MB);
    u16*    OP1  = (u16*)(w + 16 * MB);
    float*  PfA  = (float*)(w + 16 * MB);
    float*  F2b  = (float*)(w + 16 * MB);
    u16*    QKV  = (u16*)(w + 24 * MB);
    float*  PfB  = (float*)(w + 24 * MB);
    u16*    F1   = (u16*)(w + 24 * MB);
    u16*    A_bf = (u16*)(w + 40 * MB);
    u16*    OP0  = (u16*)(w + 40 * MB);
    u16*    AT   = (u16*)(w + 40 * MB);
    u16*    Y_bf = (u16*)(w + 40 * MB);
    float2* xtab = (float2*)(w + 62 * MB);
    float2* ML   = (float2*)(w + 62 * MB + 512 * 1024);

    // One fused prep dispatch: 12 weight transposes + x convert + xpos table
    prep_kernel<<<9472, 256, 0, stream>>>(x, Wq, Wk, Wv, Wo, W1, W2,
                                          w, R1f, A_bf, xtab);

    for (int l = 0; l < LAYERS; l++) {
        u16* WqkvT = (u16*)(w + 48 * MB + (size_t)l * 2 * MB);
        u16* WoT   = (u16*)(w + 52 * MB + (size_t)l * 1 * MB);
        u16* W1T   = (u16*)(w + 54 * MB + (size_t)l * 2 * MB);
        u16* W2T   = (u16*)(w + 58 * MB + (size_t)l * 2 * MB);
        const float* b1_l  = b1 + (size_t)l * FFN_DIM;
        const float* b2_l  = b2 + (size_t)l * HIDDEN;
        const float* g1_l  = g1 + (size_t)l * HIDDEN;
        const float* be1_l = be1 + (size_t)l * HIDDEN;
        const float* g2_l  = g2 + (size_t)l * HIDDEN;
        const float* be2_l = be2 + (size_t)l * HIDDEN;

        // QKV = A_bf @ [Wq|Wk|Wv]  (bf16 out), 128x128xBK64, 512 blocks
        gemm_mfma<128, 128, 64, 2, 0, 0, 0, 1><<<dim3(16, 32), 256, 0, stream>>>(
            A_bf, WqkvT, nullptr, QKV, nullptr, MROWS, 2048, 512);

        // fused xpos (Q,K) + V transpose
        xpos_vtrans<<<5120, 256, 0, stream>>>(QKV, xtab, VTg);

        // flash attention: XCD-swizzled grid (h, qtile, b*2+split)
        flash_attn_mfma<<<dim3(8, 16, 4), 256, 0, stream>>>(QKV, VTg, OP0, OP1, ML);
        attn_combine<<<MROWS * 1024 / 2048, 256, 0, stream>>>(OP0, OP1, ML, AT);

        // P = AT @ Wo: 128x64xBK64, 2-way split-K -> fp32 partials, 512 blocks
        gemm_mfma<128, 64, 64, 2, 1, 0, 0, 2><<<dim3(8, 32, 2), 256, 0, stream>>>(
            AT, WoT, nullptr, PfA, PfB, MROWS, 512, 1024);

        // Y = LN(A + P0 + P1)
        addln_kernel<<<MROWS, 256, 0, stream>>>(R1f, PfA, PfB, g1_l, be1_l, Yf, Y_bf);

        // F1 = relu(Y @ W1 + b1) (bf16 out), 128x128xBK64, 512 blocks
        gemm_mfma<128, 128, 64, 2, 0, 1, 1, 1><<<dim3(16, 32), 256, 0, stream>>>(
            Y_bf, W1T, b1_l, F1, nullptr, MROWS, 2048, 512);

        // F2 = F1 @ W2 + b2: 128x64xBK64, 2-way split-K -> fp32 partials
        gemm_mfma<128, 64, 64, 2, 1, 1, 0, 2><<<dim3(8, 32, 2), 256, 0, stream>>>(
            F1, W2T, b2_l, F2a, F2b, MROWS, 512, 2048);

        // x_next = LN(Y + F2a + F2b)
        float* dstf = (l == LAYERS - 1) ? out : R1f;
        addln_kernel<<<MROWS, 256, 0, stream>>>(Yf, F2a, F2b, g2_l, be2_l, dstf, A_bf);
    }
}